// Round 4
// baseline (275.046 us; speedup 1.0000x reference)
//
#include <hip/hip_runtime.h>
#include <hip/hip_bf16.h>
#include <cstdint>

typedef __attribute__((ext_vector_type(8))) short short8;
typedef __attribute__((ext_vector_type(4))) float f32x4;
typedef __attribute__((ext_vector_type(16))) float f32x16;
typedef __attribute__((ext_vector_type(4))) unsigned uint4v;

#define DEV static __device__ __forceinline__

DEV f32x4 mfma16(short8 a, short8 b, f32x4 c) {
    return __builtin_amdgcn_mfma_f32_16x16x32_bf16(a, b, c, 0, 0, 0);
}
DEV f32x16 mfma32(short8 a, short8 b, f32x16 c) {
    return __builtin_amdgcn_mfma_f32_32x32x16_bf16(a, b, c, 0, 0, 0);
}

DEV unsigned short f2bf(float f) {
    __hip_bfloat16 h = __float2bfloat16(f);
    return __builtin_bit_cast(unsigned short, h);
}

// pack two f32 -> two bf16 in a u32 (lo = first arg), RNE
DEV unsigned cvtpk(float lo, float hi) {
    unsigned r;
    asm("v_cvt_pk_bf16_f32 %0, %1, %2" : "=v"(r) : "v"(lo), "v"(hi));
    return r;
}
// vdst_hi <-> vsrc_lo swap: after, a = {a_lo, b_lo}, b = {a_hi, b_hi}
DEV void plswap(unsigned& a, unsigned& b) {
    asm volatile("v_permlane32_swap_b32 %0, %1" : "+v"(a), "+v"(b));
}

// global -> LDS direct load, 16B per lane. Dest: wave-uniform base + lane*16.
#define GLOAD16(gp, lp)                                                        \
    __builtin_amdgcn_global_load_lds(                                          \
        (const __attribute__((address_space(1))) unsigned int*)(uintptr_t)(gp),\
        (__attribute__((address_space(3))) unsigned int*)(uintptr_t)(lp),      \
        16, 0, 0)

// ---------------- prep kernels ----------------

__global__ void pe_kernel(float* __restrict__ pe) {
    int i = threadIdx.x;
    if (i >= 512) return;
    float div = expf((float)(2 * i) * (-9.210340371976184f / 1024.0f));
    pe[2 * i]          = 0.0f;      // sin(0*div)
    pe[2 * i + 1]      = 1.0f;      // cos(0*div)
    pe[1024 + 2 * i]     = sinf(div);
    pe[1024 + 2 * i + 1] = cosf(div);
}

__global__ void cvt_bf16(const float* __restrict__ src, unsigned short* __restrict__ dst, int n4) {
    int stride = gridDim.x * blockDim.x;
    for (int i = blockIdx.x * blockDim.x + threadIdx.x; i < n4; i += stride) {
        float4 v = ((const float4*)src)[i];
        ushort4 o;
        o.x = f2bf(v.x); o.y = f2bf(v.y); o.z = f2bf(v.z); o.w = f2bf(v.w);
        ((ushort4*)dst)[i] = o;
    }
}

// mask [2048,2048] int32 (0/1) -> bit-words [2048][64]
__global__ void pack_mask(const int* __restrict__ mask, unsigned int* __restrict__ words) {
    int w = blockIdx.x * blockDim.x + threadIdx.x;   // 0..131071
    const int4* m4 = (const int4*)mask + (size_t)w * 8;
    unsigned int bits = 0;
#pragma unroll
    for (int j = 0; j < 8; j++) {
        int4 v = m4[j];
        bits |= (unsigned)(v.x & 1) << (4 * j);
        bits |= (unsigned)(v.y & 1) << (4 * j + 1);
        bits |= (unsigned)(v.z & 1) << (4 * j + 2);
        bits |= (unsigned)(v.w & 1) << (4 * j + 3);
    }
    words[w] = bits;
}

// ---------------- GEMM mainloop (128x128 tile, BK=32, 4 waves 2x2, K=1024) ----------------
DEV void gemm_mainloop(const unsigned short* __restrict__ A,
                       const unsigned short* __restrict__ Bm,
                       int m0, int n0, f32x4 (&acc)[4][4],
                       unsigned short* As, unsigned short* Bs) {
    const int t = threadIdx.x;
    const int w = t >> 6;
    const int l = t & 63, lr = l & 15, lg = l >> 4;
    const int wr = w >> 1, wc = w & 1;
    const int srow = t >> 2;
    const int scol = (t & 3) * 8;
#pragma unroll
    for (int i = 0; i < 4; i++)
#pragma unroll
        for (int j = 0; j < 4; j++) acc[i][j] = f32x4{0.f, 0.f, 0.f, 0.f};

    const unsigned short* Ap = A + (size_t)(m0 + srow) * 1024 + scol;
    const unsigned short* Bp = Bm + (size_t)(n0 + srow) * 1024 + scol;
    unsigned short* dA = As + w * 512;
    unsigned short* dB = Bs + w * 512;

    for (int k0 = 0; k0 < 1024; k0 += 32) {
        GLOAD16(Ap + k0, dA);
        GLOAD16(Ap + 64 * 1024 + k0, dA + 2048);
        GLOAD16(Bp + k0, dB);
        GLOAD16(Bp + 64 * 1024 + k0, dB + 2048);
        __syncthreads();
        short8 af[4], bfr[4];
#pragma unroll
        for (int i = 0; i < 4; i++)
            af[i] = *(const short8*)(As + (wr * 64 + i * 16 + lr) * 32 + lg * 8);
#pragma unroll
        for (int j = 0; j < 4; j++)
            bfr[j] = *(const short8*)(Bs + (wc * 64 + j * 16 + lr) * 32 + lg * 8);
#pragma unroll
        for (int i = 0; i < 4; i++)
#pragma unroll
            for (int j = 0; j < 4; j++)
                acc[i][j] = mfma16(af[i], bfr[j], acc[i][j]);
        __syncthreads();
    }
}

// qkv GEMM: epilogue +bias, +pe (q,k), q *= 1/8*log2e; scatter q,k -> [B,H,S,64]; v -> [B,H,64,S]
__global__ __launch_bounds__(256) void qkv_gemm(
    const unsigned short* __restrict__ x, const unsigned short* __restrict__ wq,
    const float* __restrict__ bias, const float* __restrict__ pe,
    unsigned short* __restrict__ qo, unsigned short* __restrict__ ko,
    unsigned short* __restrict__ vt) {
    __shared__ unsigned short As[128 * 32], Bs[128 * 32];
    const int m0 = blockIdx.y * 128, n0 = blockIdx.x * 128;
    f32x4 acc[4][4];
    gemm_mainloop(x, wq, m0, n0, acc, As, Bs);

    const int t = threadIdx.x, w = t >> 6, l = t & 63;
    const int wr = w >> 1, wc = w & 1, lr = l & 15, lg = l >> 4;
#pragma unroll
    for (int i = 0; i < 4; i++) {
#pragma unroll
        for (int j = 0; j < 4; j++) {
            const int n = n0 + wc * 64 + j * 16 + lr;
            const int part = n >> 10, d = n & 1023, h = d >> 6, hd = d & 63;
            const float bia = bias[n];
#pragma unroll
            for (int r = 0; r < 4; r++) {
                const int m = m0 + wr * 64 + i * 16 + lg * 4 + r;
                const int b = m >> 11, s = m & 2047;
                float v = acc[i][j][r] + bia;
                if (part == 0) {
                    v = (v + pe[b * 1024 + d]) * 0.1803368801111204f; // 1/8 * log2(e)
                    qo[((size_t)(b * 16 + h) * 2048 + s) * 64 + hd] = f2bf(v);
                } else if (part == 1) {
                    v += pe[b * 1024 + d];
                    ko[((size_t)(b * 16 + h) * 2048 + s) * 64 + hd] = f2bf(v);
                } else {
                    vt[((size_t)(b * 16 + h) * 64 + hd) * 2048 + s] = f2bf(v);
                }
            }
        }
    }
}

// fc GEMM: M=4096, N=1024, out f32 += fc_b
__global__ __launch_bounds__(256) void fc_gemm(
    const unsigned short* __restrict__ a, const unsigned short* __restrict__ wf,
    const float* __restrict__ bias, float* __restrict__ out) {
    __shared__ unsigned short As[128 * 32], Bs[128 * 32];
    const int m0 = blockIdx.y * 128, n0 = blockIdx.x * 128;
    f32x4 acc[4][4];
    gemm_mainloop(a, wf, m0, n0, acc, As, Bs);

    const int t = threadIdx.x, w = t >> 6, l = t & 63;
    const int wr = w >> 1, wc = w & 1, lr = l & 15, lg = l >> 4;
#pragma unroll
    for (int i = 0; i < 4; i++) {
#pragma unroll
        for (int j = 0; j < 4; j++) {
            const int n = n0 + wc * 64 + j * 16 + lr;
            const float bia = bias[n];
#pragma unroll
            for (int r = 0; r < 4; r++) {
                const int m = m0 + wr * 64 + i * 16 + lg * 4 + r;
                out[(size_t)m * 1024 + n] = acc[i][j][r] + bia;
            }
        }
    }
}

// ---------------- split-K flash attention: 32x32 MFMA, swapped QK, in-register softmax ----
// SPLIT=4 chunks of 512 keys. 1 wave per block, 32 q-rows, KBLK=32.
// Lane (c = l&31, hi = l>>5). S^T = mfma(K,Q): col c = q; kr = (reg&3)+8*(reg>>2)+4*hi.
// Emits UNNORMALIZED partial O~^T (f32, [64 d][32 q]) + per-q stats (m, l).
// XCD swizzle: bid&7 = xcd; 4 (b,h) pairs per xcd -> K/V L2-resident.
__global__ __launch_bounds__(64) void attn(
    const unsigned short* __restrict__ q, const unsigned short* __restrict__ k,
    const unsigned short* __restrict__ vt, const unsigned int* __restrict__ mw,
    float* __restrict__ po, float* __restrict__ ms) {
    const int l = threadIdx.x, c = l & 31, hi = l >> 5;
    const int bid = blockIdx.x;
    const int xcd = bid & 7, idx = bid >> 3;        // idx 0..1023
    const int bh = xcd * 4 + (idx & 3);
    const int t2 = idx >> 2;                        // 0..255
    const int chunk = t2 & 3, qb = t2 >> 2;         // chunk 0..3, qb 0..63
    const int q0 = qb * 32;
    const int tile = bh * 64 + qb;
    const int kb0 = chunk * 16;

    const unsigned short* qbase = q + (size_t)bh * 2048 * 64;
    const unsigned short* kbase = k + (size_t)bh * 2048 * 64;
    const unsigned short* vbase = vt + (size_t)bh * 64 * 2048;

    // Q B-frag: lane holds Q[q0+c][dstep*16 + hi*8 ..+7]
    short8 qf[4];
#pragma unroll
    for (int d = 0; d < 4; d++)
        qf[d] = *(const short8*)(qbase + (q0 + c) * 64 + d * 16 + hi * 8);

    const unsigned short* kp  = kbase + c * 64 + hi * 8;
    const unsigned short* vp0 = vbase + c * 2048 + hi * 8;         // d = c
    const unsigned short* vp1 = vbase + (32 + c) * 2048 + hi * 8;  // d = 32+c
    const unsigned int*   mp  = mw + (q0 + c) * 64;

    // preload first tile of this chunk
    short8 kf[4], vf[2][2];
#pragma unroll
    for (int d = 0; d < 4; d++) kf[d] = *(const short8*)(kp + kb0 * 2048 + d * 16);
#pragma unroll
    for (int kc = 0; kc < 2; kc++) {
        vf[0][kc] = *(const short8*)(vp0 + kb0 * 32 + kc * 16);
        vf[1][kc] = *(const short8*)(vp1 + kb0 * 32 + kc * 16);
    }
    unsigned int wd = mp[kb0];

    f32x16 OT0, OT1;
#pragma unroll
    for (int i = 0; i < 16; i++) { OT0[i] = 0.f; OT1[i] = 0.f; }
    float mrow = -3.0e38f, lrow = 0.f;

#pragma unroll 2
    for (int kb = kb0; kb < kb0 + 16; kb++) {
        // QK^T (K already in regs from prefetch)
        f32x16 S;
#pragma unroll
        for (int i = 0; i < 16; i++) S[i] = 0.f;
#pragma unroll
        for (int d = 0; d < 4; d++) S = mfma32(kf[d], qf[d], S);

        // prefetch tile kb+1 (tail prefetch reads adjacent ws buffers: safe, unused)
        short8 kn[4], vn[2][2];
        const unsigned short* kpn = kp + (kb + 1) * 2048;
#pragma unroll
        for (int d = 0; d < 4; d++) kn[d] = *(const short8*)(kpn + d * 16);
#pragma unroll
        for (int kc = 0; kc < 2; kc++) {
            vn[0][kc] = *(const short8*)(vp0 + (kb + 1) * 32 + kc * 16);
            vn[1][kc] = *(const short8*)(vp1 + (kb + 1) * 32 + kc * 16);
        }
        const unsigned int wn = mp[kb + 1];

        // mask + softmax (all in-lane; q = c for both halves)
        const unsigned int wds = wd >> (4 * hi);
        float p[16];
#pragma unroll
        for (int g = 0; g < 4; g++)
#pragma unroll
            for (int u = 0; u < 4; u++)
                p[g * 4 + u] = (wds & (1u << (8 * g + u))) ? -1e9f : S[g * 4 + u];

        float mx = fmaxf(fmaxf(fmaxf(fmaxf(p[0], p[1]), fmaxf(p[2], p[3])),
                               fmaxf(fmaxf(p[4], p[5]), fmaxf(p[6], p[7]))),
                         fmaxf(fmaxf(fmaxf(p[8], p[9]), fmaxf(p[10], p[11])),
                               fmaxf(fmaxf(p[12], p[13]), fmaxf(p[14], p[15]))));
        mx = fmaxf(mx, __shfl_xor(mx, 32));
        if (!__all(mx <= mrow + 8.0f)) {      // defer-max (T13)
            float mn = fmaxf(mrow, mx);
            float a = exp2f(mrow - mn);
            mrow = mn;
            lrow *= a;
#pragma unroll
            for (int i = 0; i < 16; i++) { OT0[i] *= a; OT1[i] *= a; }
        }
#pragma unroll
        for (int i = 0; i < 16; i++) p[i] = exp2f(p[i] - mrow);
        float rs = (((p[0] + p[1]) + (p[2] + p[3])) + ((p[4] + p[5]) + (p[6] + p[7]))) +
                   (((p[8] + p[9]) + (p[10] + p[11])) + ((p[12] + p[13]) + (p[14] + p[15])));
        rs += __shfl_xor(rs, 32);
        lrow += rs;

        // P -> bf16 A-frag: 8 cvt_pk + 4 permlane32_swap (T12)
        unsigned w8[8];
#pragma unroll
        for (int g = 0; g < 4; g++) {
            w8[2 * g]     = cvtpk(p[4 * g], p[4 * g + 1]);
            w8[2 * g + 1] = cvtpk(p[4 * g + 2], p[4 * g + 3]);
        }
        short8 pa[2];
#pragma unroll
        for (int kc = 0; kc < 2; kc++) {
            unsigned a0 = w8[4 * kc], a2 = w8[4 * kc + 2];
            plswap(a0, a2);
            unsigned a1 = w8[4 * kc + 1], a3 = w8[4 * kc + 3];
            plswap(a1, a3);
            uint4v tv; tv[0] = a0; tv[1] = a1; tv[2] = a2; tv[3] = a3;
            pa[kc] = __builtin_bit_cast(short8, tv);
        }

        // PV: O^T[d][q] += V^T * P
        OT0 = mfma32(vf[0][0], pa[0], OT0);
        OT0 = mfma32(vf[0][1], pa[1], OT0);
        OT1 = mfma32(vf[1][0], pa[0], OT1);
        OT1 = mfma32(vf[1][1], pa[1], OT1);

#pragma unroll
        for (int d = 0; d < 4; d++) kf[d] = kn[d];
#pragma unroll
        for (int kc = 0; kc < 2; kc++) { vf[0][kc] = vn[0][kc]; vf[1][kc] = vn[1][kc]; }
        wd = wn;
    }

    // emit partials: stats (m, l) for q = c, and unnormalized O~^T [64][32]
    if (hi == 0) {
        float2 st; st.x = mrow; st.y = lrow;
        *(float2*)(ms + ((size_t)tile * 4 + chunk) * 64 + c * 2) = st;
    }
    float* pb = po + ((size_t)tile * 4 + chunk) * 2048;   // [64 d][32 q]
#pragma unroll
    for (int i = 0; i < 16; i++) {
        const int kr = (i & 3) + 8 * (i >> 2) + 4 * hi;
        pb[kr * 32 + c]        = OT0[i];
        pb[(32 + kr) * 32 + c] = OT1[i];
    }
}

// combine partials: one wave per (bh, qb) tile. lane: q = l>>1, dh = (l&1)*32.
__global__ __launch_bounds__(64) void combine(
    const float* __restrict__ po, const float* __restrict__ ms,
    unsigned short* __restrict__ ao) {
    const int cid = blockIdx.x;                 // 0..2047 = bh*64 + qb
    const int bh = cid >> 6, qb = cid & 63;
    const int b = bh >> 4, h = bh & 15, q0 = qb * 32;
    const int l = threadIdx.x, q = l >> 1, dh = (l & 1) * 32;

    const float* msb = ms + (size_t)cid * 4 * 64;
    float m[4], li[4];
    float M = -3.0e38f;
#pragma unroll
    for (int i = 0; i < 4; i++) {
        float2 st = *(const float2*)(msb + i * 64 + q * 2);
        m[i] = st.x; li[i] = st.y;
        M = fmaxf(M, m[i]);
    }
    float w[4], L = 0.f;
#pragma unroll
    for (int i = 0; i < 4; i++) { w[i] = exp2f(m[i] - M); L += w[i] * li[i]; }
    const float inv = 1.0f / L;

    const float* pb = po + (size_t)cid * 4 * 2048;   // [4][64][32]
    float acc[32];
#pragma unroll
    for (int j = 0; j < 32; j++) acc[j] = 0.f;
#pragma unroll
    for (int i = 0; i < 4; i++)
#pragma unroll
        for (int j = 0; j < 32; j++)
            acc[j] += w[i] * pb[i * 2048 + (dh + j) * 32 + q];

    unsigned short* gout = ao + ((size_t)(b * 2048 + q0 + q)) * 1024 + h * 64 + dh;
#pragma unroll
    for (int ch = 0; ch < 4; ch++) {
        uint4v pk;
#pragma unroll
        for (int u = 0; u < 4; u++)
            pk[u] = cvtpk(acc[ch * 8 + 2 * u] * inv, acc[ch * 8 + 2 * u + 1] * inv);
        *(uint4v*)(gout + ch * 8) = pk;
    }
}

// ---------------- launcher ----------------
extern "C" void kernel_launch(void* const* d_in, const int* in_sizes, int n_in,
                              void* d_out, int out_size, void* d_ws, size_t ws_size,
                              hipStream_t stream) {
    const float* x     = (const float*)d_in[0];
    const int*   mask  = (const int*)d_in[1];
    const float* qkv_w = (const float*)d_in[2];
    const float* qkv_b = (const float*)d_in[3];
    const float* fc_w  = (const float*)d_in[4];
    const float* fc_b  = (const float*)d_in[5];
    float* out = (float*)d_out;

    char* ws = (char*)d_ws;
    size_t off = 0;
    auto alloc = [&](size_t bytes) {
        off = (off + 255) & ~(size_t)255;
        void* p = ws + off;
        off += bytes;
        return p;
    };
    float*          pe     = (float*)alloc(2 * 1024 * 4);
    unsigned int*   mwords = (unsigned int*)alloc((size_t)2048 * 64 * 4);
    unsigned short* xb     = (unsigned short*)alloc((size_t)4096 * 1024 * 2);
    unsigned short* wqkv   = (unsigned short*)alloc((size_t)3072 * 1024 * 2);
    unsigned short* wfc    = (unsigned short*)alloc((size_t)1024 * 1024 * 2);
    unsigned short* qb16   = (unsigned short*)alloc((size_t)2 * 16 * 2048 * 64 * 2);
    unsigned short* kb16   = (unsigned short*)alloc((size_t)2 * 16 * 2048 * 64 * 2);
    unsigned short* vtb    = (unsigned short*)alloc((size_t)2 * 16 * 64 * 2048 * 2);
    unsigned short* attn_o = (unsigned short*)alloc((size_t)4096 * 1024 * 2);
    float*          po     = (float*)alloc((size_t)2048 * 4 * 64 * 32 * 4);
    float*          msb    = (float*)alloc((size_t)2048 * 4 * 32 * 2 * 4);

    pe_kernel<<<1, 512, 0, stream>>>(pe);
    cvt_bf16<<<1024, 256, 0, stream>>>(x, xb, 4096 * 1024 / 4);
    cvt_bf16<<<768, 256, 0, stream>>>(qkv_w, wqkv, 3072 * 1024 / 4);
    cvt_bf16<<<256, 256, 0, stream>>>(fc_w, wfc, 1024 * 1024 / 4);
    pack_mask<<<512, 256, 0, stream>>>(mask, mwords);
    qkv_gemm<<<dim3(24, 32), 256, 0, stream>>>(xb, wqkv, qkv_b, pe, qb16, kb16, vtb);
    attn<<<dim3(8192), 64, 0, stream>>>(qb16, kb16, vtb, mwords, po, msb);
    combine<<<dim3(2048), 64, 0, stream>>>(po, msb, attn_o);
    fc_gemm<<<dim3(8, 32), 256, 0, stream>>>(attn_o, wfc, fc_b, out);
}

// Round 5
// 273.976 us; speedup vs baseline: 1.0039x; 1.0039x over previous
//
#include <hip/hip_runtime.h>
#include <hip/hip_bf16.h>
#include <cstdint>

typedef __attribute__((ext_vector_type(8))) short short8;
typedef __attribute__((ext_vector_type(4))) float f32x4;
typedef __attribute__((ext_vector_type(16))) float f32x16;
typedef __attribute__((ext_vector_type(4))) unsigned uint4v;

#define DEV static __device__ __forceinline__

DEV f32x4 mfma16(short8 a, short8 b, f32x4 c) {
    return __builtin_amdgcn_mfma_f32_16x16x32_bf16(a, b, c, 0, 0, 0);
}
DEV f32x16 mfma32(short8 a, short8 b, f32x16 c) {
    return __builtin_amdgcn_mfma_f32_32x32x16_bf16(a, b, c, 0, 0, 0);
}

DEV unsigned short f2bf(float f) {
    __hip_bfloat16 h = __float2bfloat16(f);
    return __builtin_bit_cast(unsigned short, h);
}

// pack two f32 -> two bf16 in a u32 (lo = first arg), RNE
DEV unsigned cvtpk(float lo, float hi) {
    unsigned r;
    asm("v_cvt_pk_bf16_f32 %0, %1, %2" : "=v"(r) : "v"(lo), "v"(hi));
    return r;
}
// vdst_hi <-> vsrc_lo swap: after, a = {a_lo, b_lo}, b = {a_hi, b_hi}
DEV void plswap(unsigned& a, unsigned& b) {
    asm volatile("v_permlane32_swap_b32 %0, %1" : "+v"(a), "+v"(b));
}

// global -> LDS direct load, 16B per lane. Dest: wave-uniform base + lane*16.
#define GLOAD16(gp, lp)                                                        \
    __builtin_amdgcn_global_load_lds(                                          \
        (const __attribute__((address_space(1))) unsigned int*)(uintptr_t)(gp),\
        (__attribute__((address_space(3))) unsigned int*)(uintptr_t)(lp),      \
        16, 0, 0)

// ---------------- prep kernels ----------------

__global__ void pe_kernel(float* __restrict__ pe) {
    int i = threadIdx.x;
    if (i >= 512) return;
    float div = expf((float)(2 * i) * (-9.210340371976184f / 1024.0f));
    pe[2 * i]          = 0.0f;      // sin(0*div)
    pe[2 * i + 1]      = 1.0f;      // cos(0*div)
    pe[1024 + 2 * i]     = sinf(div);
    pe[1024 + 2 * i + 1] = cosf(div);
}

__global__ void cvt_bf16(const float* __restrict__ src, unsigned short* __restrict__ dst, int n4) {
    int stride = gridDim.x * blockDim.x;
    for (int i = blockIdx.x * blockDim.x + threadIdx.x; i < n4; i += stride) {
        float4 v = ((const float4*)src)[i];
        ushort4 o;
        o.x = f2bf(v.x); o.y = f2bf(v.y); o.z = f2bf(v.z); o.w = f2bf(v.w);
        ((ushort4*)dst)[i] = o;
    }
}

// mask [2048,2048] int32 (0/1) -> bit-words [2048][64]
__global__ void pack_mask(const int* __restrict__ mask, unsigned int* __restrict__ words) {
    int w = blockIdx.x * blockDim.x + threadIdx.x;   // 0..131071
    const int4* m4 = (const int4*)mask + (size_t)w * 8;
    unsigned int bits = 0;
#pragma unroll
    for (int j = 0; j < 8; j++) {
        int4 v = m4[j];
        bits |= (unsigned)(v.x & 1) << (4 * j);
        bits |= (unsigned)(v.y & 1) << (4 * j + 1);
        bits |= (unsigned)(v.z & 1) << (4 * j + 2);
        bits |= (unsigned)(v.w & 1) << (4 * j + 3);
    }
    words[w] = bits;
}

// ---------------- GEMM mainloop (128x128 tile, BK=32, 4 waves 2x2, K=1024) ----------------
DEV void gemm_mainloop(const unsigned short* __restrict__ A,
                       const unsigned short* __restrict__ Bm,
                       int m0, int n0, f32x4 (&acc)[4][4],
                       unsigned short* As, unsigned short* Bs) {
    const int t = threadIdx.x;
    const int w = t >> 6;
    const int l = t & 63, lr = l & 15, lg = l >> 4;
    const int wr = w >> 1, wc = w & 1;
    const int srow = t >> 2;
    const int scol = (t & 3) * 8;
#pragma unroll
    for (int i = 0; i < 4; i++)
#pragma unroll
        for (int j = 0; j < 4; j++) acc[i][j] = f32x4{0.f, 0.f, 0.f, 0.f};

    const unsigned short* Ap = A + (size_t)(m0 + srow) * 1024 + scol;
    const unsigned short* Bp = Bm + (size_t)(n0 + srow) * 1024 + scol;
    unsigned short* dA = As + w * 512;
    unsigned short* dB = Bs + w * 512;

    for (int k0 = 0; k0 < 1024; k0 += 32) {
        GLOAD16(Ap + k0, dA);
        GLOAD16(Ap + 64 * 1024 + k0, dA + 2048);
        GLOAD16(Bp + k0, dB);
        GLOAD16(Bp + 64 * 1024 + k0, dB + 2048);
        __syncthreads();
        short8 af[4], bfr[4];
#pragma unroll
        for (int i = 0; i < 4; i++)
            af[i] = *(const short8*)(As + (wr * 64 + i * 16 + lr) * 32 + lg * 8);
#pragma unroll
        for (int j = 0; j < 4; j++)
            bfr[j] = *(const short8*)(Bs + (wc * 64 + j * 16 + lr) * 32 + lg * 8);
#pragma unroll
        for (int i = 0; i < 4; i++)
#pragma unroll
            for (int j = 0; j < 4; j++)
                acc[i][j] = mfma16(af[i], bfr[j], acc[i][j]);
        __syncthreads();
    }
}

// qkv GEMM: epilogue +bias, +pe (q,k), q *= 1/8*log2e; scatter q,k -> [B,H,S,64]; v -> [B,H,64,S]
__global__ __launch_bounds__(256) void qkv_gemm(
    const unsigned short* __restrict__ x, const unsigned short* __restrict__ wq,
    const float* __restrict__ bias, const float* __restrict__ pe,
    unsigned short* __restrict__ qo, unsigned short* __restrict__ ko,
    unsigned short* __restrict__ vt) {
    __shared__ unsigned short As[128 * 32], Bs[128 * 32];
    const int m0 = blockIdx.y * 128, n0 = blockIdx.x * 128;
    f32x4 acc[4][4];
    gemm_mainloop(x, wq, m0, n0, acc, As, Bs);

    const int t = threadIdx.x, w = t >> 6, l = t & 63;
    const int wr = w >> 1, wc = w & 1, lr = l & 15, lg = l >> 4;
#pragma unroll
    for (int i = 0; i < 4; i++) {
#pragma unroll
        for (int j = 0; j < 4; j++) {
            const int n = n0 + wc * 64 + j * 16 + lr;
            const int part = n >> 10, d = n & 1023, h = d >> 6, hd = d & 63;
            const float bia = bias[n];
#pragma unroll
            for (int r = 0; r < 4; r++) {
                const int m = m0 + wr * 64 + i * 16 + lg * 4 + r;
                const int b = m >> 11, s = m & 2047;
                float v = acc[i][j][r] + bia;
                if (part == 0) {
                    v = (v + pe[b * 1024 + d]) * 0.1803368801111204f; // 1/8 * log2(e)
                    qo[((size_t)(b * 16 + h) * 2048 + s) * 64 + hd] = f2bf(v);
                } else if (part == 1) {
                    v += pe[b * 1024 + d];
                    ko[((size_t)(b * 16 + h) * 2048 + s) * 64 + hd] = f2bf(v);
                } else {
                    vt[((size_t)(b * 16 + h) * 64 + hd) * 2048 + s] = f2bf(v);
                }
            }
        }
    }
}

// fc GEMM: M=4096, N=1024, out f32 += fc_b
__global__ __launch_bounds__(256) void fc_gemm(
    const unsigned short* __restrict__ a, const unsigned short* __restrict__ wf,
    const float* __restrict__ bias, float* __restrict__ out) {
    __shared__ unsigned short As[128 * 32], Bs[128 * 32];
    const int m0 = blockIdx.y * 128, n0 = blockIdx.x * 128;
    f32x4 acc[4][4];
    gemm_mainloop(a, wf, m0, n0, acc, As, Bs);

    const int t = threadIdx.x, w = t >> 6, l = t & 63;
    const int wr = w >> 1, wc = w & 1, lr = l & 15, lg = l >> 4;
#pragma unroll
    for (int i = 0; i < 4; i++) {
#pragma unroll
        for (int j = 0; j < 4; j++) {
            const int n = n0 + wc * 64 + j * 16 + lr;
            const float bia = bias[n];
#pragma unroll
            for (int r = 0; r < 4; r++) {
                const int m = m0 + wr * 64 + i * 16 + lg * 4 + r;
                out[(size_t)m * 1024 + n] = acc[i][j][r] + bia;
            }
        }
    }
}

// ---------------- split-K flash attention: 4 waves/block, 32x32 MFMA, swapped QK ----------
// Grid 2048 x 256thr. Block = (bh, chunk, qgroup); wave w handles qb = qgroup*4 + w.
// 4 waves share the K/V chunk stream (L1/L2 reuse), no barriers, no LDS.
// Lane (c = l&31, hi = l>>5). S^T = mfma(K,Q): col c = q; kr = (reg&3)+8*(reg>>2)+4*hi.
// Emits UNNORMALIZED partial O~^T (f32, [64 d][32 q]) + per-q stats (m, l).
// XCD swizzle: bid&7 = xcd; 4 (b,h) pairs per xcd -> K/V L2-resident.
__global__ __launch_bounds__(256) void attn(
    const unsigned short* __restrict__ q, const unsigned short* __restrict__ k,
    const unsigned short* __restrict__ vt, const unsigned int* __restrict__ mw,
    float* __restrict__ po, float* __restrict__ ms) {
    const int t = threadIdx.x, w = t >> 6;
    const int l = t & 63, c = l & 31, hi = l >> 5;
    const int bid = blockIdx.x;
    const int xcd = bid & 7, idx = bid >> 3;        // idx 0..255
    const int bh = xcd * 4 + (idx & 3);
    const int rest = idx >> 2;                      // 0..63
    const int chunk = rest & 3, qg = rest >> 2;     // chunk 0..3, qgroup 0..15
    const int qb = qg * 4 + w;                      // 0..63
    const int q0 = qb * 32;
    const int tile = bh * 64 + qb;
    const int kb0 = chunk * 16;

    const unsigned short* qbase = q + (size_t)bh * 2048 * 64;
    const unsigned short* kbase = k + (size_t)bh * 2048 * 64;
    const unsigned short* vbase = vt + (size_t)bh * 64 * 2048;

    // Q B-frag: lane holds Q[q0+c][dstep*16 + hi*8 ..+7]
    short8 qf[4];
#pragma unroll
    for (int d = 0; d < 4; d++)
        qf[d] = *(const short8*)(qbase + (q0 + c) * 64 + d * 16 + hi * 8);

    const unsigned short* kp  = kbase + c * 64 + hi * 8;
    const unsigned short* vp0 = vbase + c * 2048 + hi * 8;         // d = c
    const unsigned short* vp1 = vbase + (32 + c) * 2048 + hi * 8;  // d = 32+c
    const unsigned int*   mp  = mw + (q0 + c) * 64;

    // preload first tile of this chunk
    short8 kf[4], vf[2][2];
#pragma unroll
    for (int d = 0; d < 4; d++) kf[d] = *(const short8*)(kp + kb0 * 2048 + d * 16);
#pragma unroll
    for (int kc = 0; kc < 2; kc++) {
        vf[0][kc] = *(const short8*)(vp0 + kb0 * 32 + kc * 16);
        vf[1][kc] = *(const short8*)(vp1 + kb0 * 32 + kc * 16);
    }
    unsigned int wd = mp[kb0];

    f32x16 OT0, OT1;
#pragma unroll
    for (int i = 0; i < 16; i++) { OT0[i] = 0.f; OT1[i] = 0.f; }
    float mrow = -3.0e38f, lrow = 0.f;

#pragma unroll 2
    for (int kb = kb0; kb < kb0 + 16; kb++) {
        // QK^T (K already in regs from prefetch)
        f32x16 S;
#pragma unroll
        for (int i = 0; i < 16; i++) S[i] = 0.f;
#pragma unroll
        for (int d = 0; d < 4; d++) S = mfma32(kf[d], qf[d], S);

        // prefetch tile kb+1 (tail prefetch reads adjacent ws buffers: safe, unused)
        short8 kn[4], vn[2][2];
        const unsigned short* kpn = kp + (kb + 1) * 2048;
#pragma unroll
        for (int d = 0; d < 4; d++) kn[d] = *(const short8*)(kpn + d * 16);
#pragma unroll
        for (int kc = 0; kc < 2; kc++) {
            vn[0][kc] = *(const short8*)(vp0 + (kb + 1) * 32 + kc * 16);
            vn[1][kc] = *(const short8*)(vp1 + (kb + 1) * 32 + kc * 16);
        }
        const unsigned int wn = mp[kb + 1];

        // mask + softmax (all in-lane; q = c for both halves)
        const unsigned int wds = wd >> (4 * hi);
        float p[16];
#pragma unroll
        for (int g = 0; g < 4; g++)
#pragma unroll
            for (int u = 0; u < 4; u++)
                p[g * 4 + u] = (wds & (1u << (8 * g + u))) ? -1e9f : S[g * 4 + u];

        float mx = fmaxf(fmaxf(fmaxf(fmaxf(p[0], p[1]), fmaxf(p[2], p[3])),
                               fmaxf(fmaxf(p[4], p[5]), fmaxf(p[6], p[7]))),
                         fmaxf(fmaxf(fmaxf(p[8], p[9]), fmaxf(p[10], p[11])),
                               fmaxf(fmaxf(p[12], p[13]), fmaxf(p[14], p[15]))));
        mx = fmaxf(mx, __shfl_xor(mx, 32));
        if (!__all(mx <= mrow + 8.0f)) {      // defer-max (T13)
            float mn = fmaxf(mrow, mx);
            float a = exp2f(mrow - mn);
            mrow = mn;
            lrow *= a;
#pragma unroll
            for (int i = 0; i < 16; i++) { OT0[i] *= a; OT1[i] *= a; }
        }
#pragma unroll
        for (int i = 0; i < 16; i++) p[i] = exp2f(p[i] - mrow);
        float rs = (((p[0] + p[1]) + (p[2] + p[3])) + ((p[4] + p[5]) + (p[6] + p[7]))) +
                   (((p[8] + p[9]) + (p[10] + p[11])) + ((p[12] + p[13]) + (p[14] + p[15])));
        rs += __shfl_xor(rs, 32);
        lrow += rs;

        // P -> bf16 A-frag: 8 cvt_pk + 4 permlane32_swap (T12)
        unsigned w8[8];
#pragma unroll
        for (int g = 0; g < 4; g++) {
            w8[2 * g]     = cvtpk(p[4 * g], p[4 * g + 1]);
            w8[2 * g + 1] = cvtpk(p[4 * g + 2], p[4 * g + 3]);
        }
        short8 pa[2];
#pragma unroll
        for (int kc = 0; kc < 2; kc++) {
            unsigned a0 = w8[4 * kc], a2 = w8[4 * kc + 2];
            plswap(a0, a2);
            unsigned a1 = w8[4 * kc + 1], a3 = w8[4 * kc + 3];
            plswap(a1, a3);
            uint4v tv; tv[0] = a0; tv[1] = a1; tv[2] = a2; tv[3] = a3;
            pa[kc] = __builtin_bit_cast(short8, tv);
        }

        // PV: O^T[d][q] += V^T * P
        OT0 = mfma32(vf[0][0], pa[0], OT0);
        OT0 = mfma32(vf[0][1], pa[1], OT0);
        OT1 = mfma32(vf[1][0], pa[0], OT1);
        OT1 = mfma32(vf[1][1], pa[1], OT1);

#pragma unroll
        for (int d = 0; d < 4; d++) kf[d] = kn[d];
#pragma unroll
        for (int kc = 0; kc < 2; kc++) { vf[0][kc] = vn[0][kc]; vf[1][kc] = vn[1][kc]; }
        wd = wn;
    }

    // emit partials: stats (m, l) for q = c, and unnormalized O~^T [64][32]
    if (hi == 0) {
        float2 st; st.x = mrow; st.y = lrow;
        *(float2*)(ms + ((size_t)tile * 4 + chunk) * 64 + c * 2) = st;
    }
    float* pb = po + ((size_t)tile * 4 + chunk) * 2048;   // [64 d][32 q]
#pragma unroll
    for (int i = 0; i < 16; i++) {
        const int kr = (i & 3) + 8 * (i >> 2) + 4 * hi;
        pb[kr * 32 + c]        = OT0[i];
        pb[(32 + kr) * 32 + c] = OT1[i];
    }
}

// combine partials: one wave per (bh, qb) tile. lane: q = l>>1, dh = (l&1)*32.
__global__ __launch_bounds__(64) void combine(
    const float* __restrict__ po, const float* __restrict__ ms,
    unsigned short* __restrict__ ao) {
    const int cid = blockIdx.x;                 // 0..2047 = bh*64 + qb
    const int bh = cid >> 6, qb = cid & 63;
    const int b = bh >> 4, h = bh & 15, q0 = qb * 32;
    const int l = threadIdx.x, q = l >> 1, dh = (l & 1) * 32;

    const float* msb = ms + (size_t)cid * 4 * 64;
    float m[4], li[4];
    float M = -3.0e38f;
#pragma unroll
    for (int i = 0; i < 4; i++) {
        float2 st = *(const float2*)(msb + i * 64 + q * 2);
        m[i] = st.x; li[i] = st.y;
        M = fmaxf(M, m[i]);
    }
    float w[4], L = 0.f;
#pragma unroll
    for (int i = 0; i < 4; i++) { w[i] = exp2f(m[i] - M); L += w[i] * li[i]; }
    const float inv = 1.0f / L;

    const float* pb = po + (size_t)cid * 4 * 2048;   // [4][64][32]
    float acc[32];
#pragma unroll
    for (int j = 0; j < 32; j++) acc[j] = 0.f;
#pragma unroll
    for (int i = 0; i < 4; i++)
#pragma unroll
        for (int j = 0; j < 32; j++)
            acc[j] += w[i] * pb[i * 2048 + (dh + j) * 32 + q];

    unsigned short* gout = ao + ((size_t)(b * 2048 + q0 + q)) * 1024 + h * 64 + dh;
#pragma unroll
    for (int ch = 0; ch < 4; ch++) {
        uint4v pk;
#pragma unroll
        for (int u = 0; u < 4; u++)
            pk[u] = cvtpk(acc[ch * 8 + 2 * u] * inv, acc[ch * 8 + 2 * u + 1] * inv);
        *(uint4v*)(gout + ch * 8) = pk;
    }
}

// ---------------- launcher ----------------
extern "C" void kernel_launch(void* const* d_in, const int* in_sizes, int n_in,
                              void* d_out, int out_size, void* d_ws, size_t ws_size,
                              hipStream_t stream) {
    const float* x     = (const float*)d_in[0];
    const int*   mask  = (const int*)d_in[1];
    const float* qkv_w = (const float*)d_in[2];
    const float* qkv_b = (const float*)d_in[3];
    const float* fc_w  = (const float*)d_in[4];
    const float* fc_b  = (const float*)d_in[5];
    float* out = (float*)d_out;

    char* ws = (char*)d_ws;
    size_t off = 0;
    auto alloc = [&](size_t bytes) {
        off = (off + 255) & ~(size_t)255;
        void* p = ws + off;
        off += bytes;
        return p;
    };
    float*          pe     = (float*)alloc(2 * 1024 * 4);
    unsigned int*   mwords = (unsigned int*)alloc((size_t)2048 * 64 * 4);
    unsigned short* xb     = (unsigned short*)alloc((size_t)4096 * 1024 * 2);
    unsigned short* wqkv   = (unsigned short*)alloc((size_t)3072 * 1024 * 2);
    unsigned short* wfc    = (unsigned short*)alloc((size_t)1024 * 1024 * 2);
    unsigned short* qb16   = (unsigned short*)alloc((size_t)2 * 16 * 2048 * 64 * 2);
    unsigned short* kb16   = (unsigned short*)alloc((size_t)2 * 16 * 2048 * 64 * 2);
    unsigned short* vtb    = (unsigned short*)alloc((size_t)2 * 16 * 64 * 2048 * 2);
    unsigned short* attn_o = (unsigned short*)alloc((size_t)4096 * 1024 * 2);
    float*          po     = (float*)alloc((size_t)2048 * 4 * 64 * 32 * 4);
    float*          msb    = (float*)alloc((size_t)2048 * 4 * 32 * 2 * 4);

    pe_kernel<<<1, 512, 0, stream>>>(pe);
    cvt_bf16<<<1024, 256, 0, stream>>>(x, xb, 4096 * 1024 / 4);
    cvt_bf16<<<768, 256, 0, stream>>>(qkv_w, wqkv, 3072 * 1024 / 4);
    cvt_bf16<<<256, 256, 0, stream>>>(fc_w, wfc, 1024 * 1024 / 4);
    pack_mask<<<512, 256, 0, stream>>>(mask, mwords);
    qkv_gemm<<<dim3(24, 32), 256, 0, stream>>>(xb, wqkv, qkv_b, pe, qb16, kb16, vtb);
    attn<<<dim3(2048), 256, 0, stream>>>(qb16, kb16, vtb, mwords, po, msb);
    combine<<<dim3(2048), 64, 0, stream>>>(po, msb, attn_o);
    fc_gemm<<<dim3(8, 32), 256, 0, stream>>>(attn_o, wfc, fc_b, out);
}

// Round 6
// 200.114 us; speedup vs baseline: 1.3744x; 1.3691x over previous
//
#include <hip/hip_runtime.h>
#include <hip/hip_bf16.h>
#include <cstdint>

typedef __attribute__((ext_vector_type(8))) short short8;
typedef __attribute__((ext_vector_type(4))) float f32x4;
typedef __attribute__((ext_vector_type(16))) float f32x16;
typedef __attribute__((ext_vector_type(4))) unsigned uint4v;

#define DEV static __device__ __forceinline__

DEV f32x4 mfma16(short8 a, short8 b, f32x4 c) {
    return __builtin_amdgcn_mfma_f32_16x16x32_bf16(a, b, c, 0, 0, 0);
}
DEV f32x16 mfma32(short8 a, short8 b, f32x16 c) {
    return __builtin_amdgcn_mfma_f32_32x32x16_bf16(a, b, c, 0, 0, 0);
}

DEV unsigned short f2bf(float f) {
    __hip_bfloat16 h = __float2bfloat16(f);
    return __builtin_bit_cast(unsigned short, h);
}

// pack two f32 -> two bf16 in a u32 (lo = first arg), RNE
DEV unsigned cvtpk(float lo, float hi) {
    unsigned r;
    asm("v_cvt_pk_bf16_f32 %0, %1, %2" : "=v"(r) : "v"(lo), "v"(hi));
    return r;
}
// vdst_hi <-> vsrc_lo swap: after, a = {a_lo, b_lo}, b = {a_hi, b_hi}
DEV void plswap(unsigned& a, unsigned& b) {
    asm volatile("v_permlane32_swap_b32 %0, %1" : "+v"(a), "+v"(b));
}

// global -> LDS direct load, 16B per lane. Dest: wave-uniform base + lane*16.
#define GLOAD16(gp, lp)                                                        \
    __builtin_amdgcn_global_load_lds(                                          \
        (const __attribute__((address_space(1))) unsigned int*)(uintptr_t)(gp),\
        (__attribute__((address_space(3))) unsigned int*)(uintptr_t)(lp),      \
        16, 0, 0)

// ---------------- prep kernels ----------------

__global__ void pe_kernel(float* __restrict__ pe) {
    int i = threadIdx.x;
    if (i >= 512) return;
    float div = expf((float)(2 * i) * (-9.210340371976184f / 1024.0f));
    pe[2 * i]          = 0.0f;      // sin(0*div)
    pe[2 * i + 1]      = 1.0f;      // cos(0*div)
    pe[1024 + 2 * i]     = sinf(div);
    pe[1024 + 2 * i + 1] = cosf(div);
}

__global__ void cvt_bf16(const float* __restrict__ src, unsigned short* __restrict__ dst, int n4) {
    int stride = gridDim.x * blockDim.x;
    for (int i = blockIdx.x * blockDim.x + threadIdx.x; i < n4; i += stride) {
        float4 v = ((const float4*)src)[i];
        ushort4 o;
        o.x = f2bf(v.x); o.y = f2bf(v.y); o.z = f2bf(v.z); o.w = f2bf(v.w);
        ((ushort4*)dst)[i] = o;
    }
}

// mask [2048,2048] int32 (0/1) -> TRANSPOSED bit-words wT[kb][row] (kb 0..63, row 0..2047)
// Thread o: kb = o>>11, row = o&2047 -> coalesced writes; each thread reads one
// contiguous 128B row-segment mask[row][kb*32..+31].
__global__ void pack_mask(const int* __restrict__ mask, unsigned int* __restrict__ wT) {
    int o = blockIdx.x * blockDim.x + threadIdx.x;   // 0..131071
    int kb = o >> 11, row = o & 2047;
    const int4* m4 = (const int4*)(mask + (size_t)row * 2048 + kb * 32);
    unsigned int bits = 0;
#pragma unroll
    for (int j = 0; j < 8; j++) {
        int4 v = m4[j];
        bits |= (unsigned)(v.x & 1) << (4 * j);
        bits |= (unsigned)(v.y & 1) << (4 * j + 1);
        bits |= (unsigned)(v.z & 1) << (4 * j + 2);
        bits |= (unsigned)(v.w & 1) << (4 * j + 3);
    }
    wT[o] = bits;
}

// ---------------- GEMM mainloop (128x128 tile, BK=32, 4 waves 2x2, K=1024) ----------------
DEV void gemm_mainloop(const unsigned short* __restrict__ A,
                       const unsigned short* __restrict__ Bm,
                       int m0, int n0, f32x4 (&acc)[4][4],
                       unsigned short* As, unsigned short* Bs) {
    const int t = threadIdx.x;
    const int w = t >> 6;
    const int l = t & 63, lr = l & 15, lg = l >> 4;
    const int wr = w >> 1, wc = w & 1;
    const int srow = t >> 2;
    const int scol = (t & 3) * 8;
#pragma unroll
    for (int i = 0; i < 4; i++)
#pragma unroll
        for (int j = 0; j < 4; j++) acc[i][j] = f32x4{0.f, 0.f, 0.f, 0.f};

    const unsigned short* Ap = A + (size_t)(m0 + srow) * 1024 + scol;
    const unsigned short* Bp = Bm + (size_t)(n0 + srow) * 1024 + scol;
    unsigned short* dA = As + w * 512;
    unsigned short* dB = Bs + w * 512;

    for (int k0 = 0; k0 < 1024; k0 += 32) {
        GLOAD16(Ap + k0, dA);
        GLOAD16(Ap + 64 * 1024 + k0, dA + 2048);
        GLOAD16(Bp + k0, dB);
        GLOAD16(Bp + 64 * 1024 + k0, dB + 2048);
        __syncthreads();
        short8 af[4], bfr[4];
#pragma unroll
        for (int i = 0; i < 4; i++)
            af[i] = *(const short8*)(As + (wr * 64 + i * 16 + lr) * 32 + lg * 8);
#pragma unroll
        for (int j = 0; j < 4; j++)
            bfr[j] = *(const short8*)(Bs + (wc * 64 + j * 16 + lr) * 32 + lg * 8);
#pragma unroll
        for (int i = 0; i < 4; i++)
#pragma unroll
            for (int j = 0; j < 4; j++)
                acc[i][j] = mfma16(af[i], bfr[j], acc[i][j]);
        __syncthreads();
    }
}

// qkv GEMM: epilogue +bias, +pe (q,k), q *= 1/8*log2e; scatter into FRAGMENT-MAJOR
// layouts so the attn kernel's loads are lane-coalesced (addr = base + lane*16B):
//   Q/K per (bh, tile t=s>>5): off = bh*131072 + t*2048 + (hd>>4)*512
//                                    + (((hd>>3)&1)*32 + (s&31))*8 + (hd&7)
//   V  per (bh, tile kb=s>>5): off = bh*131072 + kb*2048 + (hd>>5)*1024 + ((s>>4)&1)*512
//                                    + (((s>>3)&1)*32 + (hd&31))*8 + (s&7)
__global__ __launch_bounds__(256) void qkv_gemm(
    const unsigned short* __restrict__ x, const unsigned short* __restrict__ wq,
    const float* __restrict__ bias, const float* __restrict__ pe,
    unsigned short* __restrict__ qo, unsigned short* __restrict__ ko,
    unsigned short* __restrict__ vt) {
    __shared__ unsigned short As[128 * 32], Bs[128 * 32];
    const int m0 = blockIdx.y * 128, n0 = blockIdx.x * 128;
    f32x4 acc[4][4];
    gemm_mainloop(x, wq, m0, n0, acc, As, Bs);

    const int t = threadIdx.x, w = t >> 6, l = t & 63;
    const int wr = w >> 1, wc = w & 1, lr = l & 15, lg = l >> 4;
#pragma unroll
    for (int i = 0; i < 4; i++) {
#pragma unroll
        for (int j = 0; j < 4; j++) {
            const int n = n0 + wc * 64 + j * 16 + lr;
            const int part = n >> 10, d = n & 1023, h = d >> 6, hd = d & 63;
            const float bia = bias[n];
#pragma unroll
            for (int r = 0; r < 4; r++) {
                const int m = m0 + wr * 64 + i * 16 + lg * 4 + r;
                const int b = m >> 11, s = m & 2047;
                const int bh = b * 16 + h;
                float v = acc[i][j][r] + bia;
                if (part == 2) {
                    const size_t off = (size_t)bh * 131072 + (s >> 5) * 2048 +
                                       (hd >> 5) * 1024 + ((s >> 4) & 1) * 512 +
                                       (((s >> 3) & 1) * 32 + (hd & 31)) * 8 + (s & 7);
                    vt[off] = f2bf(v);
                } else {
                    const size_t off = (size_t)bh * 131072 + (s >> 5) * 2048 +
                                       (hd >> 4) * 512 +
                                       (((hd >> 3) & 1) * 32 + (s & 31)) * 8 + (hd & 7);
                    if (part == 0) {
                        v = (v + pe[b * 1024 + d]) * 0.1803368801111204f; // 1/8 * log2(e)
                        qo[off] = f2bf(v);
                    } else {
                        v += pe[b * 1024 + d];
                        ko[off] = f2bf(v);
                    }
                }
            }
        }
    }
}

// fc GEMM: M=4096, N=1024, out f32 += fc_b
__global__ __launch_bounds__(256) void fc_gemm(
    const unsigned short* __restrict__ a, const unsigned short* __restrict__ wf,
    const float* __restrict__ bias, float* __restrict__ out) {
    __shared__ unsigned short As[128 * 32], Bs[128 * 32];
    const int m0 = blockIdx.y * 128, n0 = blockIdx.x * 128;
    f32x4 acc[4][4];
    gemm_mainloop(a, wf, m0, n0, acc, As, Bs);

    const int t = threadIdx.x, w = t >> 6, l = t & 63;
    const int wr = w >> 1, wc = w & 1, lr = l & 15, lg = l >> 4;
#pragma unroll
    for (int i = 0; i < 4; i++) {
#pragma unroll
        for (int j = 0; j < 4; j++) {
            const int n = n0 + wc * 64 + j * 16 + lr;
            const float bia = bias[n];
#pragma unroll
            for (int r = 0; r < 4; r++) {
                const int m = m0 + wr * 64 + i * 16 + lg * 4 + r;
                out[(size_t)m * 1024 + n] = acc[i][j][r] + bia;
            }
        }
    }
}

// ---------------- split-K flash attention: fragment-major coalesced loads ----------------
// Grid 2048 x 256thr (4 waves). Block = (bh, chunk, qgroup); wave w: qb = qgroup*4 + w.
// ALL global loads are addr = fragbase + lane*16B (perfectly coalesced, no LDS).
// Lane (c = l&31, hi = l>>5). S^T = mfma(K,Q): col c = q; kr = (reg&3)+8*(reg>>2)+4*hi.
// Emits UNNORMALIZED partial O~^T (f32, [64 d][32 q]) + per-q stats (m, l).
// XCD swizzle: bid&7 = xcd; 4 (b,h) pairs per xcd -> K/V L2-resident.
__global__ __launch_bounds__(256) void attn(
    const unsigned short* __restrict__ q, const unsigned short* __restrict__ k,
    const unsigned short* __restrict__ vt, const unsigned int* __restrict__ mw,
    float* __restrict__ po, float* __restrict__ ms) {
    const int t = threadIdx.x, w = t >> 6;
    const int l = t & 63, c = l & 31, hi = l >> 5;
    const int bid = blockIdx.x;
    const int xcd = bid & 7, idx = bid >> 3;        // idx 0..255
    const int bh = xcd * 4 + (idx & 3);
    const int rest = idx >> 2;                      // 0..63
    const int chunk = rest & 3, qg = rest >> 2;     // chunk 0..3, qgroup 0..15
    const int qb = qg * 4 + w;                      // 0..63
    const int q0 = qb * 32;
    const int tile = bh * 64 + qb;
    const int kb0 = chunk * 16;

    // fragment-major bases; every load below is  ptr + lane*8 shorts (16B)
    const unsigned short* qfb = q + (size_t)bh * 131072 + qb * 2048 + l * 8;
    const unsigned short* kfb = k + (size_t)bh * 131072 + l * 8;
    const unsigned short* vfb = vt + (size_t)bh * 131072 + l * 8;

    short8 qf[4];
#pragma unroll
    for (int d = 0; d < 4; d++)
        qf[d] = *(const short8*)(qfb + d * 512);

    // preload first tile of this chunk
    short8 kf[4], vf[2][2];
#pragma unroll
    for (int d = 0; d < 4; d++) kf[d] = *(const short8*)(kfb + kb0 * 2048 + d * 512);
#pragma unroll
    for (int kc = 0; kc < 2; kc++) {
        vf[0][kc] = *(const short8*)(vfb + kb0 * 2048 + kc * 512);
        vf[1][kc] = *(const short8*)(vfb + kb0 * 2048 + 1024 + kc * 512);
    }
    unsigned int wd = mw[kb0 * 2048 + q0 + c];

    f32x16 OT0, OT1;
#pragma unroll
    for (int i = 0; i < 16; i++) { OT0[i] = 0.f; OT1[i] = 0.f; }
    float mrow = -3.0e38f, lrow = 0.f;

#pragma unroll 2
    for (int kb = kb0; kb < kb0 + 16; kb++) {
        // QK^T (K already in regs from prefetch)
        f32x16 S;
#pragma unroll
        for (int i = 0; i < 16; i++) S[i] = 0.f;
#pragma unroll
        for (int d = 0; d < 4; d++) S = mfma32(kf[d], qf[d], S);

        // prefetch tile kb+1 (tail prefetch reads adjacent ws buffers: safe, unused)
        short8 kn[4], vn[2][2];
        const unsigned short* kpn = kfb + (kb + 1) * 2048;
        const unsigned short* vpn = vfb + (kb + 1) * 2048;
#pragma unroll
        for (int d = 0; d < 4; d++) kn[d] = *(const short8*)(kpn + d * 512);
#pragma unroll
        for (int kc = 0; kc < 2; kc++) {
            vn[0][kc] = *(const short8*)(vpn + kc * 512);
            vn[1][kc] = *(const short8*)(vpn + 1024 + kc * 512);
        }
        const unsigned int wn = mw[(kb + 1) * 2048 + q0 + c];

        // mask + softmax (all in-lane; q = c for both halves)
        const unsigned int wds = wd >> (4 * hi);
        float p[16];
#pragma unroll
        for (int g = 0; g < 4; g++)
#pragma unroll
            for (int u = 0; u < 4; u++)
                p[g * 4 + u] = (wds & (1u << (8 * g + u))) ? -1e9f : S[g * 4 + u];

        float mx = fmaxf(fmaxf(fmaxf(fmaxf(p[0], p[1]), fmaxf(p[2], p[3])),
                               fmaxf(fmaxf(p[4], p[5]), fmaxf(p[6], p[7]))),
                         fmaxf(fmaxf(fmaxf(p[8], p[9]), fmaxf(p[10], p[11])),
                               fmaxf(fmaxf(p[12], p[13]), fmaxf(p[14], p[15]))));
        mx = fmaxf(mx, __shfl_xor(mx, 32));
        if (!__all(mx <= mrow + 8.0f)) {      // defer-max (T13)
            float mn = fmaxf(mrow, mx);
            float a = exp2f(mrow - mn);
            mrow = mn;
            lrow *= a;
#pragma unroll
            for (int i = 0; i < 16; i++) { OT0[i] *= a; OT1[i] *= a; }
        }
#pragma unroll
        for (int i = 0; i < 16; i++) p[i] = exp2f(p[i] - mrow);
        float rs = (((p[0] + p[1]) + (p[2] + p[3])) + ((p[4] + p[5]) + (p[6] + p[7]))) +
                   (((p[8] + p[9]) + (p[10] + p[11])) + ((p[12] + p[13]) + (p[14] + p[15])));
        rs += __shfl_xor(rs, 32);
        lrow += rs;

        // P -> bf16 A-frag: 8 cvt_pk + 4 permlane32_swap (T12)
        unsigned w8[8];
#pragma unroll
        for (int g = 0; g < 4; g++) {
            w8[2 * g]     = cvtpk(p[4 * g], p[4 * g + 1]);
            w8[2 * g + 1] = cvtpk(p[4 * g + 2], p[4 * g + 3]);
        }
        short8 pa[2];
#pragma unroll
        for (int kc = 0; kc < 2; kc++) {
            unsigned a0 = w8[4 * kc], a2 = w8[4 * kc + 2];
            plswap(a0, a2);
            unsigned a1 = w8[4 * kc + 1], a3 = w8[4 * kc + 3];
            plswap(a1, a3);
            uint4v tv; tv[0] = a0; tv[1] = a1; tv[2] = a2; tv[3] = a3;
            pa[kc] = __builtin_bit_cast(short8, tv);
        }

        // PV: O^T[d][q] += V^T * P
        OT0 = mfma32(vf[0][0], pa[0], OT0);
        OT0 = mfma32(vf[0][1], pa[1], OT0);
        OT1 = mfma32(vf[1][0], pa[0], OT1);
        OT1 = mfma32(vf[1][1], pa[1], OT1);

#pragma unroll
        for (int d = 0; d < 4; d++) kf[d] = kn[d];
#pragma unroll
        for (int kc = 0; kc < 2; kc++) { vf[0][kc] = vn[0][kc]; vf[1][kc] = vn[1][kc]; }
        wd = wn;
    }

    // emit partials: stats (m, l) for q = c, and unnormalized O~^T [64][32]
    if (hi == 0) {
        float2 st; st.x = mrow; st.y = lrow;
        *(float2*)(ms + ((size_t)tile * 4 + chunk) * 64 + c * 2) = st;
    }
    float* pb = po + ((size_t)tile * 4 + chunk) * 2048;   // [64 d][32 q]
#pragma unroll
    for (int i = 0; i < 16; i++) {
        const int kr = (i & 3) + 8 * (i >> 2) + 4 * hi;
        pb[kr * 32 + c]        = OT0[i];
        pb[(32 + kr) * 32 + c] = OT1[i];
    }
}

// combine partials: one wave per (bh, qb) tile. lane: q = l>>1, dh = (l&1)*32.
__global__ __launch_bounds__(64) void combine(
    const float* __restrict__ po, const float* __restrict__ ms,
    unsigned short* __restrict__ ao) {
    const int cid = blockIdx.x;                 // 0..2047 = bh*64 + qb
    const int bh = cid >> 6, qb = cid & 63;
    const int b = bh >> 4, h = bh & 15, q0 = qb * 32;
    const int l = threadIdx.x, q = l >> 1, dh = (l & 1) * 32;

    const float* msb = ms + (size_t)cid * 4 * 64;
    float m[4], li[4];
    float M = -3.0e38f;
#pragma unroll
    for (int i = 0; i < 4; i++) {
        float2 st = *(const float2*)(msb + i * 64 + q * 2);
        m[i] = st.x; li[i] = st.y;
        M = fmaxf(M, m[i]);
    }
    float w[4], L = 0.f;
#pragma unroll
    for (int i = 0; i < 4; i++) { w[i] = exp2f(m[i] - M); L += w[i] * li[i]; }
    const float inv = 1.0f / L;

    const float* pb = po + (size_t)cid * 4 * 2048;   // [4][64][32]
    float acc[32];
#pragma unroll
    for (int j = 0; j < 32; j++) acc[j] = 0.f;
#pragma unroll
    for (int i = 0; i < 4; i++)
#pragma unroll
        for (int j = 0; j < 32; j++)
            acc[j] += w[i] * pb[i * 2048 + (dh + j) * 32 + q];

    unsigned short* gout = ao + ((size_t)(b * 2048 + q0 + q)) * 1024 + h * 64 + dh;
#pragma unroll
    for (int ch = 0; ch < 4; ch++) {
        uint4v pk;
#pragma unroll
        for (int u = 0; u < 4; u++)
            pk[u] = cvtpk(acc[ch * 8 + 2 * u] * inv, acc[ch * 8 + 2 * u + 1] * inv);
        *(uint4v*)(gout + ch * 8) = pk;
    }
}

// ---------------- launcher ----------------
extern "C" void kernel_launch(void* const* d_in, const int* in_sizes, int n_in,
                              void* d_out, int out_size, void* d_ws, size_t ws_size,
                              hipStream_t stream) {
    const float* x     = (const float*)d_in[0];
    const int*   mask  = (const int*)d_in[1];
    const float* qkv_w = (const float*)d_in[2];
    const float* qkv_b = (const float*)d_in[3];
    const float* fc_w  = (const float*)d_in[4];
    const float* fc_b  = (const float*)d_in[5];
    float* out = (float*)d_out;

    char* ws = (char*)d_ws;
    size_t off = 0;
    auto alloc = [&](size_t bytes) {
        off = (off + 255) & ~(size_t)255;
        void* p = ws + off;
        off += bytes;
        return p;
    };
    float*          pe     = (float*)alloc(2 * 1024 * 4);
    unsigned int*   mwords = (unsigned int*)alloc((size_t)2048 * 64 * 4);
    unsigned short* xb     = (unsigned short*)alloc((size_t)4096 * 1024 * 2);
    unsigned short* wqkv   = (unsigned short*)alloc((size_t)3072 * 1024 * 2);
    unsigned short* wfc    = (unsigned short*)alloc((size_t)1024 * 1024 * 2);
    unsigned short* qb16   = (unsigned short*)alloc((size_t)2 * 16 * 2048 * 64 * 2);
    unsigned short* kb16   = (unsigned short*)alloc((size_t)2 * 16 * 2048 * 64 * 2);
    unsigned short* vtb    = (unsigned short*)alloc((size_t)2 * 16 * 64 * 2048 * 2);
    unsigned short* attn_o = (unsigned short*)alloc((size_t)4096 * 1024 * 2);
    float*          po     = (float*)alloc((size_t)2048 * 4 * 64 * 32 * 4);
    float*          msb    = (float*)alloc((size_t)2048 * 4 * 32 * 2 * 4);

    pe_kernel<<<1, 512, 0, stream>>>(pe);
    cvt_bf16<<<1024, 256, 0, stream>>>(x, xb, 4096 * 1024 / 4);
    cvt_bf16<<<768, 256, 0, stream>>>(qkv_w, wqkv, 3072 * 1024 / 4);
    cvt_bf16<<<256, 256, 0, stream>>>(fc_w, wfc, 1024 * 1024 / 4);
    pack_mask<<<512, 256, 0, stream>>>(mask, mwords);
    qkv_gemm<<<dim3(24, 32), 256, 0, stream>>>(xb, wqkv, qkv_b, pe, qb16, kb16, vtb);
    attn<<<dim3(2048), 256, 0, stream>>>(qb16, kb16, vtb, mwords, po, msb);
    combine<<<dim3(2048), 64, 0, stream>>>(po, msb, attn_o);
    fc_gemm<<<dim3(8, 32), 256, 0, stream>>>(attn_o, wfc, fc_b, out);
}

// Round 7
// 180.101 us; speedup vs baseline: 1.5272x; 1.1111x over previous
//
#include <hip/hip_runtime.h>
#include <hip/hip_bf16.h>
#include <cstdint>

typedef __attribute__((ext_vector_type(8))) short short8;
typedef __attribute__((ext_vector_type(4))) float f32x4;
typedef __attribute__((ext_vector_type(16))) float f32x16;
typedef __attribute__((ext_vector_type(4))) unsigned uint4v;

#define DEV static __device__ __forceinline__

DEV f32x4 mfma16(short8 a, short8 b, f32x4 c) {
    return __builtin_amdgcn_mfma_f32_16x16x32_bf16(a, b, c, 0, 0, 0);
}
DEV f32x16 mfma32(short8 a, short8 b, f32x16 c) {
    return __builtin_amdgcn_mfma_f32_32x32x16_bf16(a, b, c, 0, 0, 0);
}

DEV unsigned short f2bf(float f) {
    __hip_bfloat16 h = __float2bfloat16(f);
    return __builtin_bit_cast(unsigned short, h);
}

// pack two f32 -> two bf16 in a u32 (lo = first arg), RNE
DEV unsigned cvtpk(float lo, float hi) {
    unsigned r;
    asm("v_cvt_pk_bf16_f32 %0, %1, %2" : "=v"(r) : "v"(lo), "v"(hi));
    return r;
}
// vdst_hi <-> vsrc_lo swap: after, a = {a_lo, b_lo}, b = {a_hi, b_hi}
DEV void plswap(unsigned& a, unsigned& b) {
    asm volatile("v_permlane32_swap_b32 %0, %1" : "+v"(a), "+v"(b));
}

// global -> LDS direct load, 16B per lane. Dest: wave-uniform base + lane*16.
#define GLOAD16(gp, lp)                                                        \
    __builtin_amdgcn_global_load_lds(                                          \
        (const __attribute__((address_space(1))) unsigned int*)(uintptr_t)(gp),\
        (__attribute__((address_space(3))) unsigned int*)(uintptr_t)(lp),      \
        16, 0, 0)

// ---------------- prep kernels ----------------

__global__ void pe_kernel(float* __restrict__ pe) {
    int i = threadIdx.x;
    if (i >= 512) return;
    float div = expf((float)(2 * i) * (-9.210340371976184f / 1024.0f));
    pe[2 * i]          = 0.0f;      // sin(0*div)
    pe[2 * i + 1]      = 1.0f;      // cos(0*div)
    pe[1024 + 2 * i]     = sinf(div);
    pe[1024 + 2 * i + 1] = cosf(div);
}

// fused f32->bf16 conversion of x, qkv_w, fc_w (one launch). 2097152 float4s total.
__global__ void cvt3(const float* __restrict__ x, const float* __restrict__ wq,
                     const float* __restrict__ wf, unsigned short* __restrict__ xb,
                     unsigned short* __restrict__ wqb, unsigned short* __restrict__ wfb) {
    int i = blockIdx.x * blockDim.x + threadIdx.x;   // 0..2097151
    const float* src; unsigned short* dst; int off;
    if (i < 1048576)      { src = x;  dst = xb;  off = i; }
    else if (i < 1835008) { src = wq; dst = wqb; off = i - 1048576; }
    else                  { src = wf; dst = wfb; off = i - 1835008; }
    float4 v = ((const float4*)src)[off];
    ushort4 o;
    o.x = f2bf(v.x); o.y = f2bf(v.y); o.z = f2bf(v.z); o.w = f2bf(v.w);
    ((ushort4*)dst)[off] = o;
}

// mask [2048,2048] int32 (0/1) -> TRANSPOSED bit-words wT[kb][row] (kb 0..63, row 0..2047)
__global__ void pack_mask(const int* __restrict__ mask, unsigned int* __restrict__ wT) {
    int o = blockIdx.x * blockDim.x + threadIdx.x;   // 0..131071
    int kb = o >> 11, row = o & 2047;
    const int4* m4 = (const int4*)(mask + (size_t)row * 2048 + kb * 32);
    unsigned int bits = 0;
#pragma unroll
    for (int j = 0; j < 8; j++) {
        int4 v = m4[j];
        bits |= (unsigned)(v.x & 1) << (4 * j);
        bits |= (unsigned)(v.y & 1) << (4 * j + 1);
        bits |= (unsigned)(v.z & 1) << (4 * j + 2);
        bits |= (unsigned)(v.w & 1) << (4 * j + 3);
    }
    wT[o] = bits;
}

// ---------------- GEMM mainloop (128x128 tile, BK=32, 4 waves 2x2, K=1024) ----------------
DEV void gemm_mainloop(const unsigned short* __restrict__ A,
                       const unsigned short* __restrict__ Bm,
                       int m0, int n0, f32x4 (&acc)[4][4],
                       unsigned short* As, unsigned short* Bs) {
    const int t = threadIdx.x;
    const int w = t >> 6;
    const int l = t & 63, lr = l & 15, lg = l >> 4;
    const int wr = w >> 1, wc = w & 1;
    const int srow = t >> 2;
    const int scol = (t & 3) * 8;
#pragma unroll
    for (int i = 0; i < 4; i++)
#pragma unroll
        for (int j = 0; j < 4; j++) acc[i][j] = f32x4{0.f, 0.f, 0.f, 0.f};

    const unsigned short* Ap = A + (size_t)(m0 + srow) * 1024 + scol;
    const unsigned short* Bp = Bm + (size_t)(n0 + srow) * 1024 + scol;
    unsigned short* dA = As + w * 512;
    unsigned short* dB = Bs + w * 512;

    for (int k0 = 0; k0 < 1024; k0 += 32) {
        GLOAD16(Ap + k0, dA);
        GLOAD16(Ap + 64 * 1024 + k0, dA + 2048);
        GLOAD16(Bp + k0, dB);
        GLOAD16(Bp + 64 * 1024 + k0, dB + 2048);
        __syncthreads();
        short8 af[4], bfr[4];
#pragma unroll
        for (int i = 0; i < 4; i++)
            af[i] = *(const short8*)(As + (wr * 64 + i * 16 + lr) * 32 + lg * 8);
#pragma unroll
        for (int j = 0; j < 4; j++)
            bfr[j] = *(const short8*)(Bs + (wc * 64 + j * 16 + lr) * 32 + lg * 8);
#pragma unroll
        for (int i = 0; i < 4; i++)
#pragma unroll
            for (int j = 0; j < 4; j++)
                acc[i][j] = mfma16(af[i], bfr[j], acc[i][j]);
        __syncthreads();
    }
}

// qkv GEMM: epilogue +bias, +pe (q,k), q *= 1/8*log2e; scatter into FRAGMENT-MAJOR
// layouts so the attn kernel's loads are lane-coalesced (addr = base + lane*16B).
__global__ __launch_bounds__(256) void qkv_gemm(
    const unsigned short* __restrict__ x, const unsigned short* __restrict__ wq,
    const float* __restrict__ bias, const float* __restrict__ pe,
    unsigned short* __restrict__ qo, unsigned short* __restrict__ ko,
    unsigned short* __restrict__ vt) {
    __shared__ unsigned short As[128 * 32], Bs[128 * 32];
    const int m0 = blockIdx.y * 128, n0 = blockIdx.x * 128;
    f32x4 acc[4][4];
    gemm_mainloop(x, wq, m0, n0, acc, As, Bs);

    const int t = threadIdx.x, w = t >> 6, l = t & 63;
    const int wr = w >> 1, wc = w & 1, lr = l & 15, lg = l >> 4;
#pragma unroll
    for (int i = 0; i < 4; i++) {
#pragma unroll
        for (int j = 0; j < 4; j++) {
            const int n = n0 + wc * 64 + j * 16 + lr;
            const int part = n >> 10, d = n & 1023, h = d >> 6, hd = d & 63;
            const float bia = bias[n];
#pragma unroll
            for (int r = 0; r < 4; r++) {
                const int m = m0 + wr * 64 + i * 16 + lg * 4 + r;
                const int b = m >> 11, s = m & 2047;
                const int bh = b * 16 + h;
                float v = acc[i][j][r] + bia;
                if (part == 2) {
                    const size_t off = (size_t)bh * 131072 + (s >> 5) * 2048 +
                                       (hd >> 5) * 1024 + ((s >> 4) & 1) * 512 +
                                       (((s >> 3) & 1) * 32 + (hd & 31)) * 8 + (s & 7);
                    vt[off] = f2bf(v);
                } else {
                    const size_t off = (size_t)bh * 131072 + (s >> 5) * 2048 +
                                       (hd >> 4) * 512 +
                                       (((hd >> 3) & 1) * 32 + (s & 31)) * 8 + (hd & 7);
                    if (part == 0) {
                        v = (v + pe[b * 1024 + d]) * 0.1803368801111204f; // 1/8 * log2(e)
                        qo[off] = f2bf(v);
                    } else {
                        v += pe[b * 1024 + d];
                        ko[off] = f2bf(v);
                    }
                }
            }
        }
    }
}

// fc GEMM: M=4096, N=1024, out f32 += fc_b
__global__ __launch_bounds__(256) void fc_gemm(
    const unsigned short* __restrict__ a, const unsigned short* __restrict__ wf,
    const float* __restrict__ bias, float* __restrict__ out) {
    __shared__ unsigned short As[128 * 32], Bs[128 * 32];
    const int m0 = blockIdx.y * 128, n0 = blockIdx.x * 128;
    f32x4 acc[4][4];
    gemm_mainloop(a, wf, m0, n0, acc, As, Bs);

    const int t = threadIdx.x, w = t >> 6, l = t & 63;
    const int wr = w >> 1, wc = w & 1, lr = l & 15, lg = l >> 4;
#pragma unroll
    for (int i = 0; i < 4; i++) {
#pragma unroll
        for (int j = 0; j < 4; j++) {
            const int n = n0 + wc * 64 + j * 16 + lr;
            const float bia = bias[n];
#pragma unroll
            for (int r = 0; r < 4; r++) {
                const int m = m0 + wr * 64 + i * 16 + lg * 4 + r;
                out[(size_t)m * 1024 + n] = acc[i][j][r] + bia;
            }
        }
    }
}

// ---------------- split-K flash attention: no-max softmax, MFMA row-sums ----------------
// Scores in log2 domain are bounded (|s| << 100) => exp2(s) directly, NO max tracking:
// removes fmax tree, defer logic, and the s-m subtraction chain. Row-sums accumulate on
// the MFMA pipe via a ones-row A operand: LS = mfma(ones, pa, LS) (sums the exact bf16 P
// used in PV). SPLIT=2 chunks of 1024 keys. Grid 1024 x 256thr (4 waves, wave w -> qb).
// ALL global loads are addr = fragbase + lane*16B (fragment-major, R6).
// Lane (c = l&31, hi = l>>5). S^T = mfma(K,Q): col c = q; kr = (reg&3)+8*(reg>>2)+4*hi.
// Emits UNNORMALIZED partial O~^T (f32, [64 d][32 q]) + per-q sum l.
// XCD swizzle: bid&7 = xcd; 4 (b,h) pairs per xcd -> K/V L2-resident.
__global__ __launch_bounds__(256) void attn(
    const unsigned short* __restrict__ q, const unsigned short* __restrict__ k,
    const unsigned short* __restrict__ vt, const unsigned int* __restrict__ mw,
    float* __restrict__ po, float* __restrict__ ms) {
    const int t = threadIdx.x, w = t >> 6;
    const int l = t & 63, c = l & 31, hi = l >> 5;
    const int bid = blockIdx.x;
    const int xcd = bid & 7, idx = bid >> 3;        // idx 0..127
    const int bh = xcd * 4 + (idx & 3);
    const int rest = idx >> 2;                      // 0..31
    const int chunk = rest & 1, qg = rest >> 1;     // chunk 0..1, qgroup 0..15
    const int qb = qg * 4 + w;                      // 0..63
    const int q0 = qb * 32;
    const int tile = bh * 64 + qb;
    const int kb0 = chunk * 32;

    // fragment-major bases; every load below is  ptr + lane*8 shorts (16B)
    const unsigned short* qfb = q + (size_t)bh * 131072 + qb * 2048 + l * 8;
    const unsigned short* kfb = k + (size_t)bh * 131072 + l * 8;
    const unsigned short* vfb = vt + (size_t)bh * 131072 + l * 8;

    short8 qf[4];
#pragma unroll
    for (int d = 0; d < 4; d++)
        qf[d] = *(const short8*)(qfb + d * 512);

    // ones A-operand for the row-sum MFMA (bf16 1.0 = 0x3F80)
    short8 ones;
#pragma unroll
    for (int i = 0; i < 8; i++) ones[i] = (short)0x3F80;

    // preload first tile of this chunk
    short8 kf[4], vf[2][2];
#pragma unroll
    for (int d = 0; d < 4; d++) kf[d] = *(const short8*)(kfb + kb0 * 2048 + d * 512);
#pragma unroll
    for (int kc = 0; kc < 2; kc++) {
        vf[0][kc] = *(const short8*)(vfb + kb0 * 2048 + kc * 512);
        vf[1][kc] = *(const short8*)(vfb + kb0 * 2048 + 1024 + kc * 512);
    }
    unsigned int wd = mw[kb0 * 2048 + q0 + c];

    f32x16 OT0, OT1, LS;
#pragma unroll
    for (int i = 0; i < 16; i++) { OT0[i] = 0.f; OT1[i] = 0.f; LS[i] = 0.f; }

#pragma unroll 2
    for (int kb = kb0; kb < kb0 + 32; kb++) {
        // QK^T (K already in regs from prefetch)
        f32x16 S;
#pragma unroll
        for (int i = 0; i < 16; i++) S[i] = 0.f;
#pragma unroll
        for (int d = 0; d < 4; d++) S = mfma32(kf[d], qf[d], S);

        // prefetch tile kb+1 (tail prefetch reads adjacent ws buffers: safe, unused)
        short8 kn[4], vn[2][2];
        const unsigned short* kpn = kfb + (kb + 1) * 2048;
        const unsigned short* vpn = vfb + (kb + 1) * 2048;
#pragma unroll
        for (int d = 0; d < 4; d++) kn[d] = *(const short8*)(kpn + d * 512);
#pragma unroll
        for (int kc = 0; kc < 2; kc++) {
            vn[0][kc] = *(const short8*)(vpn + kc * 512);
            vn[1][kc] = *(const short8*)(vpn + 1024 + kc * 512);
        }
        const unsigned int wn = mw[(kb + 1) * 2048 + q0 + c];

        // mask -> -1e9, then p = exp2(s) directly (no max subtraction)
        const unsigned int wds = wd >> (4 * hi);
        float p[16];
#pragma unroll
        for (int g = 0; g < 4; g++)
#pragma unroll
            for (int u = 0; u < 4; u++)
                p[g * 4 + u] = (wds & (1u << (8 * g + u))) ? -1e9f : S[g * 4 + u];
#pragma unroll
        for (int i = 0; i < 16; i++) p[i] = exp2f(p[i]);

        // P -> bf16 A-frag: 8 cvt_pk + 4 permlane32_swap (T12)
        unsigned w8[8];
#pragma unroll
        for (int g = 0; g < 4; g++) {
            w8[2 * g]     = cvtpk(p[4 * g], p[4 * g + 1]);
            w8[2 * g + 1] = cvtpk(p[4 * g + 2], p[4 * g + 3]);
        }
        short8 pa[2];
#pragma unroll
        for (int kc = 0; kc < 2; kc++) {
            unsigned a0 = w8[4 * kc], a2 = w8[4 * kc + 2];
            plswap(a0, a2);
            unsigned a1 = w8[4 * kc + 1], a3 = w8[4 * kc + 3];
            plswap(a1, a3);
            uint4v tv; tv[0] = a0; tv[1] = a1; tv[2] = a2; tv[3] = a3;
            pa[kc] = __builtin_bit_cast(short8, tv);
        }

        // PV: O^T[d][q] += V^T * P ; row-sums on the MFMA pipe
        OT0 = mfma32(vf[0][0], pa[0], OT0);
        OT0 = mfma32(vf[0][1], pa[1], OT0);
        OT1 = mfma32(vf[1][0], pa[0], OT1);
        OT1 = mfma32(vf[1][1], pa[1], OT1);
        LS  = mfma32(ones,     pa[0], LS);
        LS  = mfma32(ones,     pa[1], LS);

#pragma unroll
        for (int d = 0; d < 4; d++) kf[d] = kn[d];
#pragma unroll
        for (int kc = 0; kc < 2; kc++) { vf[0][kc] = vn[0][kc]; vf[1][kc] = vn[1][kc]; }
        wd = wn;
    }

    // emit partials: sum l for q = c (all LS regs equal), and unnormalized O~^T [64][32]
    if (hi == 0)
        ms[((size_t)tile * 2 + chunk) * 32 + c] = LS[0];
    float* pb = po + ((size_t)tile * 2 + chunk) * 2048;   // [64 d][32 q]
#pragma unroll
    for (int i = 0; i < 16; i++) {
        const int kr = (i & 3) + 8 * (i >> 2) + 4 * hi;
        pb[kr * 32 + c]        = OT0[i];
        pb[(32 + kr) * 32 + c] = OT1[i];
    }
}

// combine partials: 4 waves/block, one (bh,qb) tile per wave. lane: q=l>>1, dh=(l&1)*32.
// O = (O~0 + O~1) / (l0 + l1)  (no max weighting needed -- no-max softmax partials)
__global__ __launch_bounds__(256) void combine(
    const float* __restrict__ po, const float* __restrict__ ms,
    unsigned short* __restrict__ ao) {
    const int cid = blockIdx.x * 4 + (threadIdx.x >> 6);   // 0..2047 = bh*64 + qb
    const int bh = cid >> 6, qb = cid & 63;
    const int b = bh >> 4, h = bh & 15, q0 = qb * 32;
    const int l = threadIdx.x & 63, q = l >> 1, dh = (l & 1) * 32;

    const float L = ms[(size_t)cid * 64 + q] + ms[(size_t)cid * 64 + 32 + q];
    const float inv = 1.0f / L;

    const float* pb = po + (size_t)cid * 2 * 2048;   // [2][64][32]
    unsigned short* gout = ao + ((size_t)(b * 2048 + q0 + q)) * 1024 + h * 64 + dh;
#pragma unroll
    for (int ch = 0; ch < 4; ch++) {
        uint4v pk;
#pragma unroll
        for (int u = 0; u < 4; u++) {
            const int j0 = ch * 8 + 2 * u;
            float a0 = pb[(dh + j0) * 32 + q]     + pb[2048 + (dh + j0) * 32 + q];
            float a1 = pb[(dh + j0 + 1) * 32 + q] + pb[2048 + (dh + j0 + 1) * 32 + q];
            pk[u] = cvtpk(a0 * inv, a1 * inv);
        }
        *(uint4v*)(gout + ch * 8) = pk;
    }
}

// ---------------- launcher ----------------
extern "C" void kernel_launch(void* const* d_in, const int* in_sizes, int n_in,
                              void* d_out, int out_size, void* d_ws, size_t ws_size,
                              hipStream_t stream) {
    const float* x     = (const float*)d_in[0];
    const int*   mask  = (const int*)d_in[1];
    const float* qkv_w = (const float*)d_in[2];
    const float* qkv_b = (const float*)d_in[3];
    const float* fc_w  = (const float*)d_in[4];
    const float* fc_b  = (const float*)d_in[5];
    float* out = (float*)d_out;

    char* ws = (char*)d_ws;
    size_t off = 0;
    auto alloc = [&](size_t bytes) {
        off = (off + 255) & ~(size_t)255;
        void* p = ws + off;
        off += bytes;
        return p;
    };
    float*          pe     = (float*)alloc(2 * 1024 * 4);
    unsigned int*   mwords = (unsigned int*)alloc((size_t)2048 * 64 * 4);
    unsigned short* xb     = (unsigned short*)alloc((size_t)4096 * 1024 * 2);
    unsigned short* wqkv   = (unsigned short*)alloc((size_t)3072 * 1024 * 2);
    unsigned short* wfc    = (unsigned short*)alloc((size_t)1024 * 1024 * 2);
    unsigned short* qb16   = (unsigned short*)alloc((size_t)2 * 16 * 2048 * 64 * 2);
    unsigned short* kb16   = (unsigned short*)alloc((size_t)2 * 16 * 2048 * 64 * 2);
    unsigned short* vtb    = (unsigned short*)alloc((size_t)2 * 16 * 64 * 2048 * 2);
    unsigned short* attn_o = (unsigned short*)alloc((size_t)4096 * 1024 * 2);
    float*          po     = (float*)alloc((size_t)2048 * 2 * 2048 * 4);
    float*          msb    = (float*)alloc((size_t)2048 * 2 * 32 * 4);

    pe_kernel<<<1, 512, 0, stream>>>(pe);
    cvt3<<<8192, 256, 0, stream>>>(x, qkv_w, fc_w, xb, wqkv, wfc);
    pack_mask<<<512, 256, 0, stream>>>(mask, mwords);
    qkv_gemm<<<dim3(24, 32), 256, 0, stream>>>(xb, wqkv, qkv_b, pe, qb16, kb16, vtb);
    attn<<<dim3(1024), 256, 0, stream>>>(qb16, kb16, vtb, mwords, po, msb);
    combine<<<dim3(512), 256, 0, stream>>>(po, msb, attn_o);
    fc_gemm<<<dim3(8, 32), 256, 0, stream>>>(attn_o, wfc, fc_b, out);
}

// Round 9
// 169.509 us; speedup vs baseline: 1.6226x; 1.0625x over previous
//
#include <hip/hip_runtime.h>
#include <hip/hip_bf16.h>
#include <cstdint>

typedef __attribute__((ext_vector_type(8))) short short8;
typedef __attribute__((ext_vector_type(4))) float f32x4;
typedef __attribute__((ext_vector_type(16))) float f32x16;
typedef __attribute__((ext_vector_type(4))) unsigned uint4v;

#define DEV static __device__ __forceinline__

DEV f32x4 mfma16(short8 a, short8 b, f32x4 c) {
    return __builtin_amdgcn_mfma_f32_16x16x32_bf16(a, b, c, 0, 0, 0);
}
DEV f32x16 mfma32(short8 a, short8 b, f32x16 c) {
    return __builtin_amdgcn_mfma_f32_32x32x16_bf16(a, b, c, 0, 0, 0);
}

DEV unsigned short f2bf(float f) {
    __hip_bfloat16 h = __float2bfloat16(f);
    return __builtin_bit_cast(unsigned short, h);
}

// pack two f32 -> two bf16 in a u32 (lo = first arg), RNE
DEV unsigned cvtpk(float lo, float hi) {
    unsigned r;
    asm("v_cvt_pk_bf16_f32 %0, %1, %2" : "=v"(r) : "v"(lo), "v"(hi));
    return r;
}
// vdst_hi <-> vsrc_lo swap: after, a = {a_lo, b_lo}, b = {a_hi, b_hi}
DEV void plswap(unsigned& a, unsigned& b) {
    asm volatile("v_permlane32_swap_b32 %0, %1" : "+v"(a), "+v"(b));
}

// global -> LDS direct load, 16B per lane. Dest: wave-uniform base + lane*16.
#define GLOAD16(gp, lp)                                                        \
    __builtin_amdgcn_global_load_lds(                                          \
        (const __attribute__((address_space(1))) unsigned int*)(uintptr_t)(gp),\
        (__attribute__((address_space(3))) unsigned int*)(uintptr_t)(lp),      \
        16, 0, 0)

// ---------------- prep kernels ----------------

__global__ void pe_kernel(float* __restrict__ pe) {
    int i = threadIdx.x;
    if (i >= 512) return;
    float div = expf((float)(2 * i) * (-9.210340371976184f / 1024.0f));
    pe[2 * i]          = 0.0f;      // sin(0*div)
    pe[2 * i + 1]      = 1.0f;      // cos(0*div)
    pe[1024 + 2 * i]     = sinf(div);
    pe[1024 + 2 * i + 1] = cosf(div);
}

// fused f32->bf16 conversion of x, qkv_w, fc_w (one launch). 2097152 float4s total.
__global__ void cvt3(const float* __restrict__ x, const float* __restrict__ wq,
                     const float* __restrict__ wf, unsigned short* __restrict__ xb,
                     unsigned short* __restrict__ wqb, unsigned short* __restrict__ wfb) {
    int i = blockIdx.x * blockDim.x + threadIdx.x;   // 0..2097151
    const float* src; unsigned short* dst; int off;
    if (i < 1048576)      { src = x;  dst = xb;  off = i; }
    else if (i < 1835008) { src = wq; dst = wqb; off = i - 1048576; }
    else                  { src = wf; dst = wfb; off = i - 1835008; }
    float4 v = ((const float4*)src)[off];
    ushort4 o;
    o.x = f2bf(v.x); o.y = f2bf(v.y); o.z = f2bf(v.z); o.w = f2bf(v.w);
    ((ushort4*)dst)[off] = o;
}

// mask [2048,2048] int32 (0/1) -> TRANSPOSED bit-words wT[kb][row] (kb 0..63, row 0..2047)
__global__ void pack_mask(const int* __restrict__ mask, unsigned int* __restrict__ wT) {
    int o = blockIdx.x * blockDim.x + threadIdx.x;   // 0..131071
    int kb = o >> 11, row = o & 2047;
    const int4* m4 = (const int4*)(mask + (size_t)row * 2048 + kb * 32);
    unsigned int bits = 0;
#pragma unroll
    for (int j = 0; j < 8; j++) {
        int4 v = m4[j];
        bits |= (unsigned)(v.x & 1) << (4 * j);
        bits |= (unsigned)(v.y & 1) << (4 * j + 1);
        bits |= (unsigned)(v.z & 1) << (4 * j + 2);
        bits |= (unsigned)(v.w & 1) << (4 * j + 3);
    }
    wT[o] = bits;
}

// ------- GEMM mainloop: 128x128 tile, BK=32, double-buffered LDS, swizzled reads -------
// Stage: pre-swizzled SOURCE chunk (scg) + linear LDS dest (global_load_lds reqmt);
// reads XOR the chunk slot -> 2-way banks (free). One barrier per K-step; STAGE(next)
// issued right after the barrier gets a full iteration of ds_read+MFMA to land.
DEV void gemm_mainloop(const unsigned short* __restrict__ A,
                       const unsigned short* __restrict__ Bm,
                       int m0, int n0, f32x4 (&acc)[4][4],
                       unsigned short* As, unsigned short* Bs) {   // each [2*4096]
    const int t = threadIdx.x;
    const int w = t >> 6;
    const int l = t & 63, lr = l & 15, lg = l >> 4;
    const int wr = w >> 1, wc = w & 1;
    const int srow = t >> 2;
    const int scg = ((t & 3) ^ ((t >> 3) & 3)) * 8;   // pre-swizzled source chunk
#pragma unroll
    for (int i = 0; i < 4; i++)
#pragma unroll
        for (int j = 0; j < 4; j++) acc[i][j] = f32x4{0.f, 0.f, 0.f, 0.f};

    const unsigned short* Ap = A + (size_t)(m0 + srow) * 1024 + scg;
    const unsigned short* Bp = Bm + (size_t)(n0 + srow) * 1024 + scg;
    unsigned short* dA = As + w * 512;
    unsigned short* dB = Bs + w * 512;

    // swizzled read bases (loop-invariant): slot = lg ^ ((lr>>1)&3)
    const int slot = (lg ^ ((lr >> 1) & 3)) * 8;
    const unsigned short* Ar = As + (wr * 64 + lr) * 32 + slot;
    const unsigned short* Br = Bs + (wc * 64 + lr) * 32 + slot;

#define STAGE(buf, k0)                                                \
    {                                                                 \
        GLOAD16(Ap + (k0), dA + (buf) * 4096);                        \
        GLOAD16(Ap + 64 * 1024 + (k0), dA + (buf) * 4096 + 2048);     \
        GLOAD16(Bp + (k0), dB + (buf) * 4096);                        \
        GLOAD16(Bp + 64 * 1024 + (k0), dB + (buf) * 4096 + 2048);     \
    }

    STAGE(0, 0);
#pragma unroll 2
    for (int k0 = 0; k0 < 1024; k0 += 32) {
        const int cur = (k0 >> 5) & 1;
        __syncthreads();                      // drains vmcnt: buf[cur] ready; prev reads done
        if (k0 + 32 < 1024) STAGE(cur ^ 1, k0 + 32);
        short8 af[4], bfr[4];
#pragma unroll
        for (int i = 0; i < 4; i++)
            af[i] = *(const short8*)(Ar + cur * 4096 + i * 512);
#pragma unroll
        for (int j = 0; j < 4; j++)
            bfr[j] = *(const short8*)(Br + cur * 4096 + j * 512);
#pragma unroll
        for (int i = 0; i < 4; i++)
#pragma unroll
            for (int j = 0; j < 4; j++)
                acc[i][j] = mfma16(af[i], bfr[j], acc[i][j]);
    }
#undef STAGE
}

// qkv GEMM: epilogue +bias, +pe (q,k), q *= 1/8*log2e; scatter into FRAGMENT-MAJOR
// layouts so the attn kernel's loads are lane-coalesced (addr = base + lane*16B).
__global__ __launch_bounds__(256) void qkv_gemm(
    const unsigned short* __restrict__ x, const unsigned short* __restrict__ wq,
    const float* __restrict__ bias, const float* __restrict__ pe,
    unsigned short* __restrict__ qo, unsigned short* __restrict__ ko,
    unsigned short* __restrict__ vt) {
    __shared__ unsigned short As[2 * 4096], Bs[2 * 4096];
    const int m0 = blockIdx.y * 128, n0 = blockIdx.x * 128;
    f32x4 acc[4][4];
    gemm_mainloop(x, wq, m0, n0, acc, As, Bs);

    const int t = threadIdx.x, w = t >> 6, l = t & 63;
    const int wr = w >> 1, wc = w & 1, lr = l & 15, lg = l >> 4;
#pragma unroll
    for (int i = 0; i < 4; i++) {
#pragma unroll
        for (int j = 0; j < 4; j++) {
            const int n = n0 + wc * 64 + j * 16 + lr;
            const int part = n >> 10, d = n & 1023, h = d >> 6, hd = d & 63;
            const float bia = bias[n];
#pragma unroll
            for (int r = 0; r < 4; r++) {
                const int m = m0 + wr * 64 + i * 16 + lg * 4 + r;
                const int b = m >> 11, s = m & 2047;
                const int bh = b * 16 + h;
                float v = acc[i][j][r] + bia;
                if (part == 2) {
                    const size_t off = (size_t)bh * 131072 + (s >> 5) * 2048 +
                                       (hd >> 5) * 1024 + ((s >> 4) & 1) * 512 +
                                       (((s >> 3) & 1) * 32 + (hd & 31)) * 8 + (s & 7);
                    vt[off] = f2bf(v);
                } else {
                    const size_t off = (size_t)bh * 131072 + (s >> 5) * 2048 +
                                       (hd >> 4) * 512 +
                                       (((hd >> 3) & 1) * 32 + (s & 31)) * 8 + (hd & 7);
                    if (part == 0) {
                        v = (v + pe[b * 1024 + d]) * 0.1803368801111204f; // 1/8 * log2(e)
                        qo[off] = f2bf(v);
                    } else {
                        v += pe[b * 1024 + d];
                        ko[off] = f2bf(v);
                    }
                }
            }
        }
    }
}

// fc GEMM: M=4096, N=1024, out f32 += fc_b
__global__ __launch_bounds__(256) void fc_gemm(
    const unsigned short* __restrict__ a, const unsigned short* __restrict__ wf,
    const float* __restrict__ bias, float* __restrict__ out) {
    __shared__ unsigned short As[2 * 4096], Bs[2 * 4096];
    const int m0 = blockIdx.y * 128, n0 = blockIdx.x * 128;
    f32x4 acc[4][4];
    gemm_mainloop(a, wf, m0, n0, acc, As, Bs);

    const int t = threadIdx.x, w = t >> 6, l = t & 63;
    const int wr = w >> 1, wc = w & 1, lr = l & 15, lg = l >> 4;
#pragma unroll
    for (int i = 0; i < 4; i++) {
#pragma unroll
        for (int j = 0; j < 4; j++) {
            const int n = n0 + wc * 64 + j * 16 + lr;
            const float bia = bias[n];
#pragma unroll
            for (int r = 0; r < 4; r++) {
                const int m = m0 + wr * 64 + i * 16 + lg * 4 + r;
                out[(size_t)m * 1024 + n] = acc[i][j][r] + bia;
            }
        }
    }
}

// ---------------- split-K flash attention: no-max softmax, MFMA row-sums ----------------
// (R7-proven version: bit-test mask -> -1e9 before exp2.)
// SPLIT=2 chunks of 1024 keys. Grid 1024 x 256thr (4 waves, wave w -> qb).
// ALL global loads are addr = fragbase + lane*16B (fragment-major, R6).
// Lane (c = l&31, hi = l>>5). S^T = mfma(K,Q): col c = q; kr = (reg&3)+8*(reg>>2)+4*hi.
// Emits UNNORMALIZED partial O~^T (f32, [64 d][32 q]) + per-q sum l.
// XCD swizzle: bid&7 = xcd; 4 (b,h) pairs per xcd -> K/V L2-resident.
__global__ __launch_bounds__(256) void attn(
    const unsigned short* __restrict__ q, const unsigned short* __restrict__ k,
    const unsigned short* __restrict__ vt, const unsigned int* __restrict__ mw,
    float* __restrict__ po, float* __restrict__ ms) {
    const int t = threadIdx.x, w = t >> 6;
    const int l = t & 63, c = l & 31, hi = l >> 5;
    const int bid = blockIdx.x;
    const int xcd = bid & 7, idx = bid >> 3;        // idx 0..127
    const int bh = xcd * 4 + (idx & 3);
    const int rest = idx >> 2;                      // 0..31
    const int chunk = rest & 1, qg = rest >> 1;     // chunk 0..1, qgroup 0..15
    const int qb = qg * 4 + w;                      // 0..63
    const int q0 = qb * 32;
    const int tile = bh * 64 + qb;
    const int kb0 = chunk * 32;

    // fragment-major bases; every load below is  ptr + lane*8 shorts (16B)
    const unsigned short* qfb = q + (size_t)bh * 131072 + qb * 2048 + l * 8;
    const unsigned short* kfb = k + (size_t)bh * 131072 + l * 8;
    const unsigned short* vfb = vt + (size_t)bh * 131072 + l * 8;

    short8 qf[4];
#pragma unroll
    for (int d = 0; d < 4; d++)
        qf[d] = *(const short8*)(qfb + d * 512);

    // ones A-operand for the row-sum MFMA (bf16 1.0 = 0x3F80)
    short8 ones;
#pragma unroll
    for (int i = 0; i < 8; i++) ones[i] = (short)0x3F80;

    // preload first tile of this chunk
    short8 kf[4], vf[2][2];
#pragma unroll
    for (int d = 0; d < 4; d++) kf[d] = *(const short8*)(kfb + kb0 * 2048 + d * 512);
#pragma unroll
    for (int kc = 0; kc < 2; kc++) {
        vf[0][kc] = *(const short8*)(vfb + kb0 * 2048 + kc * 512);
        vf[1][kc] = *(const short8*)(vfb + kb0 * 2048 + 1024 + kc * 512);
    }
    unsigned int wd = mw[kb0 * 2048 + q0 + c];

    f32x16 OT0, OT1, LS;
#pragma unroll
    for (int i = 0; i < 16; i++) { OT0[i] = 0.f; OT1[i] = 0.f; LS[i] = 0.f; }

#pragma unroll 2
    for (int kb = kb0; kb < kb0 + 32; kb++) {
        // QK^T (K already in regs from prefetch)
        f32x16 S;
#pragma unroll
        for (int i = 0; i < 16; i++) S[i] = 0.f;
#pragma unroll
        for (int d = 0; d < 4; d++) S = mfma32(kf[d], qf[d], S);

        // prefetch tile kb+1 (tail prefetch reads adjacent ws buffers: safe, unused)
        short8 kn[4], vn[2][2];
        const unsigned short* kpn = kfb + (kb + 1) * 2048;
        const unsigned short* vpn = vfb + (kb + 1) * 2048;
#pragma unroll
        for (int d = 0; d < 4; d++) kn[d] = *(const short8*)(kpn + d * 512);
#pragma unroll
        for (int kc = 0; kc < 2; kc++) {
            vn[0][kc] = *(const short8*)(vpn + kc * 512);
            vn[1][kc] = *(const short8*)(vpn + 1024 + kc * 512);
        }
        const unsigned int wn = mw[(kb + 1) * 2048 + q0 + c];

        // mask -> -1e9, then p = exp2(s) directly (no max subtraction)
        const unsigned int wds = wd >> (4 * hi);
        float p[16];
#pragma unroll
        for (int g = 0; g < 4; g++)
#pragma unroll
            for (int u = 0; u < 4; u++)
                p[g * 4 + u] = (wds & (1u << (8 * g + u))) ? -1e9f : S[g * 4 + u];
#pragma unroll
        for (int i = 0; i < 16; i++) p[i] = exp2f(p[i]);

        // P -> bf16 A-frag: 8 cvt_pk + 4 permlane32_swap (T12)
        unsigned w8[8];
#pragma unroll
        for (int g = 0; g < 4; g++) {
            w8[2 * g]     = cvtpk(p[4 * g], p[4 * g + 1]);
            w8[2 * g + 1] = cvtpk(p[4 * g + 2], p[4 * g + 3]);
        }
        short8 pa[2];
#pragma unroll
        for (int kc = 0; kc < 2; kc++) {
            unsigned a0 = w8[4 * kc], a2 = w8[4 * kc + 2];
            plswap(a0, a2);
            unsigned a1 = w8[4 * kc + 1], a3 = w8[4 * kc + 3];
            plswap(a1, a3);
            uint4v tv; tv[0] = a0; tv[1] = a1; tv[2] = a2; tv[3] = a3;
            pa[kc] = __builtin_bit_cast(short8, tv);
        }

        // PV: O^T[d][q] += V^T * P ; row-sums on the MFMA pipe
        OT0 = mfma32(vf[0][0], pa[0], OT0);
        OT0 = mfma32(vf[0][1], pa[1], OT0);
        OT1 = mfma32(vf[1][0], pa[0], OT1);
        OT1 = mfma32(vf[1][1], pa[1], OT1);
        LS  = mfma32(ones,     pa[0], LS);
        LS  = mfma32(ones,     pa[1], LS);

#pragma unroll
        for (int d = 0; d < 4; d++) kf[d] = kn[d];
#pragma unroll
        for (int kc = 0; kc < 2; kc++) { vf[0][kc] = vn[0][kc]; vf[1][kc] = vn[1][kc]; }
        wd = wn;
    }

    // emit partials: sum l for q = c (all LS regs equal), and unnormalized O~^T [64][32]
    if (hi == 0)
        ms[((size_t)tile * 2 + chunk) * 32 + c] = LS[0];
    float* pb = po + ((size_t)tile * 2 + chunk) * 2048;   // [64 d][32 q]
#pragma unroll
    for (int i = 0; i < 16; i++) {
        const int kr = (i & 3) + 8 * (i >> 2) + 4 * hi;
        pb[kr * 32 + c]        = OT0[i];
        pb[(32 + kr) * 32 + c] = OT1[i];
    }
}

// combine partials: 4 waves/block, one (bh,qb) tile per wave. lane: q=l>>1, dh=(l&1)*32.
// O = (O~0 + O~1) / (l0 + l1)  (no max weighting needed -- no-max softmax partials)
__global__ __launch_bounds__(256) void combine(
    const float* __restrict__ po, const float* __restrict__ ms,
    unsigned short* __restrict__ ao) {
    const int cid = blockIdx.x * 4 + (threadIdx.x >> 6);   // 0..2047 = bh*64 + qb
    const int bh = cid >> 6, qb = cid & 63;
    const int b = bh >> 4, h = bh & 15, q0 = qb * 32;
    const int l = threadIdx.x & 63, q = l >> 1, dh = (l & 1) * 32;

    const float L = ms[(size_t)cid * 64 + q] + ms[(size_t)cid * 64 + 32 + q];
    const float inv = 1.0f / L;

    const float* pb = po + (size_t)cid * 2 * 2048;   // [2][64][32]
    unsigned short* gout = ao + ((size_t)(b * 2048 + q0 + q)) * 1024 + h * 64 + dh;
#pragma unroll
    for (int ch = 0; ch < 4; ch++) {
        uint4v pk;
#pragma unroll
        for (int u = 0; u < 4; u++) {
            const int j0 = ch * 8 + 2 * u;
            float a0 = pb[(dh + j0) * 32 + q]     + pb[2048 + (dh + j0) * 32 + q];
            float a1 = pb[(dh + j0 + 1) * 32 + q] + pb[2048 + (dh + j0 + 1) * 32 + q];
            pk[u] = cvtpk(a0 * inv, a1 * inv);
        }
        *(uint4v*)(gout + ch * 8) = pk;
    }
}

// ---------------- launcher ----------------
extern "C" void kernel_launch(void* const* d_in, const int* in_sizes, int n_in,
                              void* d_out, int out_size, void* d_ws, size_t ws_size,
                              hipStream_t stream) {
    const float* x     = (const float*)d_in[0];
    const int*   mask  = (const int*)d_in[1];
    const float* qkv_w = (const float*)d_in[2];
    const float* qkv_b = (const float*)d_in[3];
    const float* fc_w  = (const float*)d_in[4];
    const float* fc_b  = (const float*)d_in[5];
    float* out = (float*)d_out;

    char* ws = (char*)d_ws;
    size_t off = 0;
    auto alloc = [&](size_t bytes) {
        off = (off + 255) & ~(size_t)255;
        void* p = ws + off;
        off += bytes;
        return p;
    };
    float*          pe     = (float*)alloc(2 * 1024 * 4);
    unsigned int*   mwords = (unsigned int*)alloc((size_t)2048 * 64 * 4);
    unsigned short* xb     = (unsigned short*)alloc((size_t)4096 * 1024 * 2);
    unsigned short* wqkv   = (unsigned short*)alloc((size_t)3072 * 1024 * 2);
    unsigned short* wfc    = (unsigned short*)alloc((size_t)1024 * 1024 * 2);
    unsigned short* qb16   = (unsigned short*)alloc((size_t)2 * 16 * 2048 * 64 * 2);
    unsigned short* kb16   = (unsigned short*)alloc((size_t)2 * 16 * 2048 * 64 * 2);
    unsigned short* vtb    = (unsigned short*)alloc((size_t)2 * 16 * 64 * 2048 * 2);
    unsigned short* attn_o = (unsigned short*)alloc((size_t)4096 * 1024 * 2);
    float*          po     = (float*)alloc((size_t)2048 * 2 * 2048 * 4);
    float*          msb    = (float*)alloc((size_t)2048 * 2 * 32 * 4);

    pe_kernel<<<1, 512, 0, stream>>>(pe);
    cvt3<<<8192, 256, 0, stream>>>(x, qkv_w, fc_w, xb, wqkv, wfc);
    pack_mask<<<512, 256, 0, stream>>>(mask, mwords);
    qkv_gemm<<<dim3(24, 32), 256, 0, stream>>>(xb, wqkv, qkv_b, pe, qb16, kb16, vtb);
    attn<<<dim3(1024), 256, 0, stream>>>(qb16, kb16, vtb, mwords, po, msb);
    combine<<<dim3(512), 256, 0, stream>>>(po, msb, attn_o);
    fc_gemm<<<dim3(8, 32), 256, 0, stream>>>(attn_o, wfc, fc_b, out);
}